// Round 7
// baseline (176.778 us; speedup 1.0000x reference)
//
#include <hip/hip_runtime.h>
#include <math.h>

#define NN 6144
#define DD 512
#define CAP 128
#define SCAN_T (6144 * 256)            // scan threads
#define HALF_U4 (NN * (NN / 4))        // uint4 per adjacency matrix

typedef __bf16 bf16_t;
typedef __bf16 bf16x8 __attribute__((ext_vector_type(8)));
typedef unsigned short u16x8 __attribute__((ext_vector_type(8)));
typedef float f32x4 __attribute__((ext_vector_type(4)));
typedef unsigned u32x4 __attribute__((ext_vector_type(4)));

__device__ __forceinline__ float bf2f(unsigned short u) {
    unsigned v = ((unsigned)u) << 16;
    return __builtin_bit_cast(float, v);
}
__device__ __forceinline__ unsigned short f2bf(float f) {
    unsigned u = __builtin_bit_cast(unsigned, f);
    u += 0x7fffu + ((u >> 16) & 1u);   // round-to-nearest-even
    return (unsigned short)(u >> 16);
}
__device__ __forceinline__ float sigmoidf_(float z) { return 1.0f / (1.0f + expf(-z)); }

// =========== d1: k_prep — wt transpose (blocks 0..127) + w_sl/w_sr (blocks 128..255) ===========
__global__ __launch_bounds__(256) void k_prep(const float* __restrict__ Wsa,
                                              const float* __restrict__ Wg,
                                              const float* __restrict__ a_sa,
                                              unsigned short* __restrict__ wt,
                                              float* __restrict__ wsl, float* __restrict__ wsr) {
    __shared__ float s[64][65];
    int bid = blockIdx.x;
    int wave = threadIdx.x >> 6, lane = threadIdx.x & 63;
    if (bid < 128) {
        int n0 = (bid & 15) * 64;
        int k0 = (bid >> 4) * 64;
        int tx = threadIdx.x & 63, ty = threadIdx.x >> 6;
        const float* src = (n0 < 512) ? Wsa : Wg;
        int nn0 = n0 & 511;
#pragma unroll
        for (int kk = 0; kk < 64; kk += 4)
            s[kk + ty][tx] = src[(size_t)(k0 + kk + ty) * 512 + nn0 + tx];
        __syncthreads();
#pragma unroll
        for (int nn = 0; nn < 64; nn += 4)
            wt[(size_t)(n0 + nn + ty) * 512 + k0 + tx] = f2bf(s[tx][nn + ty]);
    } else {
        int k = (bid - 128) * 4 + wave;         // 0..511
        int n0 = lane * 8;
        const float* wr = Wsa + (size_t)k * 512 + n0;
        float4 w0 = *(const float4*)wr, w1 = *(const float4*)(wr + 4);
        float4 l0 = *(const float4*)(a_sa + n0), l1 = *(const float4*)(a_sa + n0 + 4);
        float4 r0 = *(const float4*)(a_sa + 512 + n0), r1 = *(const float4*)(a_sa + 512 + n0 + 4);
        float sl_ = w0.x*l0.x + w0.y*l0.y + w0.z*l0.z + w0.w*l0.w
                  + w1.x*l1.x + w1.y*l1.y + w1.z*l1.z + w1.w*l1.w;
        float sr_ = w0.x*r0.x + w0.y*r0.y + w0.z*r0.z + w0.w*r0.w
                  + w1.x*r1.x + w1.y*r1.y + w1.z*r1.z + w1.w*r1.w;
#pragma unroll
        for (int off = 32; off; off >>= 1) { sl_ += __shfl_down(sl_, off); sr_ += __shfl_down(sr_, off); }
        if (lane == 0) { wsl[k] = sl_; wsr[k] = sr_; }
    }
}

// ===== d2: k_fused — {GRID-STRIDE interleaved scan -> ballot masks} + {MFMA GEMM} + {projections} =====
// blocks [0,7680): bid%5<4 -> scan; bid%5==4 -> GEMM. blocks [7680,9216): projections.
__global__ __launch_bounds__(256) void k_fused(const float* __restrict__ x,
                                               const bf16_t* __restrict__ wt,
                                               const float* __restrict__ adjA,
                                               const float* __restrict__ adjB,
                                               const float* __restrict__ Wa,
                                               const float* __restrict__ Wb,
                                               const float* __restrict__ wsl,
                                               const float* __restrict__ wsr,
                                               unsigned long long* __restrict__ maskw,
                                               unsigned short* __restrict__ h,
                                               unsigned short* __restrict__ g,
                                               float* __restrict__ xal, float* __restrict__ xar,
                                               float* __restrict__ xbl, float* __restrict__ xbr,
                                               float* __restrict__ sl, float* __restrict__ sr) {
    int bid = blockIdx.x;
    int wave = threadIdx.x >> 6, lane = threadIdx.x & 63;
    if (bid < 7680) {
        int grp = bid % 5;
        if (grp < 4) {
            // ---- interleaved scan: flat grid-stride, 64-u4 chunks, 4 ballots -> mask words ----
            int sblk = (bid / 5) * 4 + grp;          // 0..6143
            int gt = sblk * 256 + threadIdx.x;       // 0..SCAN_T-1
            int wb0 = gt - lane;                     // wave base (multiple of 64)
            const u32x4* a4 = (const u32x4*)adjA;
            const u32x4* b4 = (const u32x4*)adjB;
#pragma unroll
            for (int j = 0; j < 12; j++) {
                int f = gt + j * SCAN_T;             // flat uint4 index, < 2*HALF_U4
                u32x4 v;
                if (f < HALF_U4) v = a4[f];          // wave-uniform branch (64 | HALF_U4)
                else             v = b4[f - HALF_U4];
                unsigned long long b0 = __ballot(v[0] != 0u);
                unsigned long long b1 = __ballot(v[1] != 0u);
                unsigned long long b2 = __ballot(v[2] != 0u);
                unsigned long long b3 = __ballot(v[3] != 0u);
                int seg = (wb0 + j * SCAN_T) >> 6;   // 0..294911
                if (lane < 4) {
                    unsigned long long bb = (lane == 0) ? b0 : (lane == 1) ? b1
                                          : (lane == 2) ? b2 : b3;
                    maskw[(size_t)seg * 4 + lane] = bb;
                }
            }
        } else {
            // ---- GEMM tile: 64 rows x 64 cols, MFMA 16x16x32, A cvt in-register ----
            int tt = bid / 5;                        // 0..1535
            int row0 = (tt % (NN / 64)) * 64 + wave * 16;
            int col0 = (tt / (NN / 64)) * 64;
            int lr = lane & 15;
            int kg = (lane >> 4) * 8;

            f32x4 acc[4] = {{0,0,0,0},{0,0,0,0},{0,0,0,0},{0,0,0,0}};
            const float* ap = x + (size_t)(row0 + lr) * DD + kg;
            const bf16_t* bp = wt + (size_t)(col0 + lr) * DD + kg;

            for (int k0 = 0; k0 < DD; k0 += 32) {
                float4 a0 = *(const float4*)(ap + k0);
                float4 a1 = *(const float4*)(ap + k0 + 4);
                u16x8 au;
                au[0] = f2bf(a0.x); au[1] = f2bf(a0.y); au[2] = f2bf(a0.z); au[3] = f2bf(a0.w);
                au[4] = f2bf(a1.x); au[5] = f2bf(a1.y); au[6] = f2bf(a1.z); au[7] = f2bf(a1.w);
                bf16x8 a = __builtin_bit_cast(bf16x8, au);
#pragma unroll
                for (int n = 0; n < 4; n++) {
                    bf16x8 b = *(const bf16x8*)(bp + (size_t)n * 16 * DD + k0);
                    acc[n] = __builtin_amdgcn_mfma_f32_16x16x32_bf16(a, b, acc[n], 0, 0, 0);
                }
            }
            int dcol = lane & 15;
            int dr0 = (lane >> 4) * 4;
#pragma unroll
            for (int n = 0; n < 4; n++) {
                int col = col0 + n * 16 + dcol;
                unsigned short* dst = (col < 512) ? h : g;
                int cc = col & 511;
#pragma unroll
                for (int rr = 0; rr < 4; rr++) {
                    int mr = row0 + dr0 + rr;
                    dst[(size_t)mr * 512 + cc] = f2bf(acc[n][rr]);
                }
            }
        }
    } else {
        // ---- projections: rows pid*4+wave; 6 dot products vs x-row ----
        int pid = bid - 7680;                        // 0..1535
        int row = pid * 4 + wave;
        int k0 = lane * 8;
        const float* xr_ = x + (size_t)row * DD + k0;
        float4 v0 = *(const float4*)xr_;
        float4 v1 = *(const float4*)(xr_ + 4);
        float xv[8] = {v0.x, v0.y, v0.z, v0.w, v1.x, v1.y, v1.z, v1.w};
        float d[6] = {0, 0, 0, 0, 0, 0};
        const float* srcs[6] = {Wa + k0, Wa + 512 + k0, Wb + k0, Wb + 512 + k0, wsl + k0, wsr + k0};
#pragma unroll
        for (int q = 0; q < 6; q++) {
            float4 w0 = *(const float4*)srcs[q];
            float4 w1 = *(const float4*)(srcs[q] + 4);
            float wv[8] = {w0.x, w0.y, w0.z, w0.w, w1.x, w1.y, w1.z, w1.w};
#pragma unroll
            for (int j = 0; j < 8; j++) d[q] += xv[j] * wv[j];
        }
#pragma unroll
        for (int off = 32; off; off >>= 1)
#pragma unroll
            for (int q = 0; q < 6; q++) d[q] += __shfl_down(d[q], off);
        if (lane == 0) {
            xal[row] = d[0]; xar[row] = d[1];
            xbl[row] = d[2]; xbr[row] = d[3];
            sl[row] = d[4]; sr[row] = d[5];
        }
    }
}

// ===== d3: k_final — mask extraction + gates + attention normalize + gathers + epilogue =====
// Row i's masks: 96 words at maskw[row96 * 96], word W = seg*4+q (seg=W>>2, q=W&3),
// bit l of word W -> col = seg*256 + l*4 + q.
__global__ __launch_bounds__(256) void k_final(
    const unsigned long long* __restrict__ maskw,
    const unsigned short* __restrict__ h, const unsigned short* __restrict__ g,
    const float* __restrict__ sl, const float* __restrict__ sr,
    const float* __restrict__ xal, const float* __restrict__ xar,
    const float* __restrict__ xbl, const float* __restrict__ xbr,
    const float* __restrict__ ba, const float* __restrict__ bb,
    const float* __restrict__ bias, float* __restrict__ out) {
    int i = blockIdx.x;
    int tid = threadIdx.x;
    int wave = tid >> 6, lane = tid & 63;
    __shared__ float w[CAP];
    __shared__ int ja[CAP], jb[CAP];
    __shared__ int tot[4];
    __shared__ float s_denom, s_ga, s_gb;

    // waves 0,1 = A words 0-47 / 48-95; waves 2,3 = B words 0-47 / 48-95
    int whalf = wave & 1;
    size_t rowbase = (size_t)((wave < 2) ? i : (NN + i)) * 96;
    int widx = whalf * 48 + lane;                 // 0..95 (lanes 48..63 idle)
    unsigned long long m = (lane < 48) ? maskw[rowbase + widx] : 0ull;
    int c = __popcll(m);
    int p = c;
#pragma unroll
    for (int off = 1; off < 64; off <<= 1) {
        int t = __shfl_up(p, off);
        if (lane >= off) p += t;
    }
    if (lane == 63) tot[wave] = p;
    __syncthreads();
    int base = (wave == 1) ? tot[0] : (wave == 3) ? tot[2] : 0;
    int pos = base + p - c;
    int* dst = (wave < 2) ? ja : jb;
    while (m) {
        int b = __ffsll((long long)m) - 1;
        m &= m - 1;
        int col = (widx >> 2) * 256 + b * 4 + (widx & 3);
        if (pos < CAP) dst[pos] = col;
        pos++;
    }
    __syncthreads();
    int cA = tot[0] + tot[1]; cA = cA > CAP ? CAP : cA;
    int cB = tot[2] + tot[3]; cB = cB > CAP ? CAP : cB;

    // ---- attention weights ----
    if (tid < cA) {
        int j = ja[tid];
        float s = sl[i] + sr[j];
        float lrelu = s > 0.f ? s : 0.01f * s;
        w[tid] = expf(-lrelu);
    }
    __syncthreads();

    if (tid < 64) {
        float p2 = 0.f, gasum = 0.f, gbsum = 0.f;
        for (int t = tid; t < cA; t += 64) { p2 += w[t]; gasum += xal[ja[t]]; }
        for (int t = tid; t < cB; t += 64) gbsum += xbl[jb[t]];
#pragma unroll
        for (int off = 32; off; off >>= 1) {
            p2 += __shfl_down(p2, off);
            gasum += __shfl_down(gasum, off);
            gbsum += __shfl_down(gbsum, off);
        }
        if (tid == 0) {
            s_denom = p2;
            s_ga = sigmoidf_(gasum + xar[i] + ba[0]);
            s_gb = sigmoidf_(gbsum + xbr[i] + bb[0]);
        }
    }
    __syncthreads();
    float inv = 1.f / (s_denom + 1e-5f);
    float ga = s_ga, gb = s_gb;

    int d0 = tid * 2;
    float a0 = 0, a1 = 0, b0 = 0, b1 = 0;
#pragma unroll 4
    for (int t = 0; t < cA; t++) {
        unsigned hv = *(const unsigned*)(h + (size_t)ja[t] * 512 + d0);
        float wt_ = w[t];
        a0 += wt_ * bf2f((unsigned short)(hv & 0xffff));
        a1 += wt_ * bf2f((unsigned short)(hv >> 16));
    }
#pragma unroll 4
    for (int t = 0; t < cB; t++) {
        unsigned gv = *(const unsigned*)(g + (size_t)jb[t] * 512 + d0);
        b0 += bf2f((unsigned short)(gv & 0xffff));
        b1 += bf2f((unsigned short)(gv >> 16));
    }
    float z0 = ga * (a0 * inv) + gb * (b0 + bias[d0]);
    float z1 = ga * (a1 * inv) + gb * (b1 + bias[d0 + 1]);
    out[(size_t)i * 512 + d0]     = sigmoidf_(z0);
    out[(size_t)i * 512 + d0 + 1] = sigmoidf_(z1);
}

extern "C" void kernel_launch(void* const* d_in, const int* in_sizes, int n_in,
                              void* d_out, int out_size, void* d_ws, size_t ws_size,
                              hipStream_t stream) {
    const float* x    = (const float*)d_in[0];
    const float* adjA = (const float*)d_in[1];
    const float* adjB = (const float*)d_in[2];
    const float* Wsa  = (const float*)d_in[3];
    const float* a_sa = (const float*)d_in[4];
    const float* Wg   = (const float*)d_in[5];
    const float* bg   = (const float*)d_in[6];
    const float* Wa   = (const float*)d_in[7];
    const float* ba   = (const float*)d_in[8];
    const float* Wb   = (const float*)d_in[9];
    const float* bb   = (const float*)d_in[10];
    float* out = (float*)d_out;

    char* ws = (char*)d_ws;
    size_t off = 0;
    auto alloc = [&](size_t bytes) -> void* {
        void* p = ws + off;
        off += (bytes + 255) & ~(size_t)255;
        return p;
    };
    unsigned short* wt = (unsigned short*)alloc((size_t)1024 * DD * 2);
    unsigned short* h  = (unsigned short*)alloc((size_t)NN * DD * 2);
    unsigned short* g  = (unsigned short*)alloc((size_t)NN * DD * 2);
    unsigned long long* maskw = (unsigned long long*)alloc((size_t)294912 * 4 * 8);
    float* xal = (float*)alloc((size_t)NN * 4);
    float* xar = (float*)alloc((size_t)NN * 4);
    float* xbl = (float*)alloc((size_t)NN * 4);
    float* xbr = (float*)alloc((size_t)NN * 4);
    float* sl  = (float*)alloc((size_t)NN * 4);
    float* sr  = (float*)alloc((size_t)NN * 4);
    float* wsl = (float*)alloc((size_t)DD * 4);
    float* wsr = (float*)alloc((size_t)DD * 4);

    // d1: W^T (bf16) + w_sl/w_sr
    k_prep<<<256, 256, 0, stream>>>(Wsa, Wg, a_sa, wt, wsl, wsr);
    // d2: grid-stride interleaved scan + GEMM + projections
    k_fused<<<9216, 256, 0, stream>>>(x, (const bf16_t*)wt, adjA, adjB, Wa, Wb, wsl, wsr,
                                      maskw, h, g, xal, xar, xbl, xbr, sl, sr);
    // d3: extraction + gates + attention + gathers + epilogue
    k_final<<<NN, 256, 0, stream>>>(maskw, h, g, sl, sr, xal, xar, xbl, xbr,
                                    ba, bb, bg, out);
}

// Round 8
// 176.191 us; speedup vs baseline: 1.0033x; 1.0033x over previous
//
#include <hip/hip_runtime.h>
#include <math.h>

#define NN 6144
#define DD 512
#define CAP 128
#define SCAN_T (6144 * 256)            // scan threads
#define HALF_U4 (NN * (NN / 4))        // uint4 per adjacency matrix

typedef __bf16 bf16_t;
typedef __bf16 bf16x8 __attribute__((ext_vector_type(8)));
typedef unsigned short u16x8 __attribute__((ext_vector_type(8)));
typedef float f32x4 __attribute__((ext_vector_type(4)));
typedef unsigned u32x4 __attribute__((ext_vector_type(4)));

__device__ __forceinline__ float bf2f(unsigned short u) {
    unsigned v = ((unsigned)u) << 16;
    return __builtin_bit_cast(float, v);
}
__device__ __forceinline__ unsigned short f2bf(float f) {
    unsigned u = __builtin_bit_cast(unsigned, f);
    u += 0x7fffu + ((u >> 16) & 1u);   // round-to-nearest-even
    return (unsigned short)(u >> 16);
}
__device__ __forceinline__ float sigmoidf_(float z) { return 1.0f / (1.0f + expf(-z)); }

// =========== d1: k_prep — wt transpose (blocks 0..127) + w_sl/w_sr (blocks 128..255) ===========
__global__ __launch_bounds__(256) void k_prep(const float* __restrict__ Wsa,
                                              const float* __restrict__ Wg,
                                              const float* __restrict__ a_sa,
                                              unsigned short* __restrict__ wt,
                                              float* __restrict__ wsl, float* __restrict__ wsr) {
    __shared__ float s[64][65];
    int bid = blockIdx.x;
    int wave = threadIdx.x >> 6, lane = threadIdx.x & 63;
    if (bid < 128) {
        int n0 = (bid & 15) * 64;
        int k0 = (bid >> 4) * 64;
        int tx = threadIdx.x & 63, ty = threadIdx.x >> 6;
        const float* src = (n0 < 512) ? Wsa : Wg;
        int nn0 = n0 & 511;
#pragma unroll
        for (int kk = 0; kk < 64; kk += 4)
            s[kk + ty][tx] = src[(size_t)(k0 + kk + ty) * 512 + nn0 + tx];
        __syncthreads();
#pragma unroll
        for (int nn = 0; nn < 64; nn += 4)
            wt[(size_t)(n0 + nn + ty) * 512 + k0 + tx] = f2bf(s[tx][nn + ty]);
    } else {
        int k = (bid - 128) * 4 + wave;         // 0..511
        int n0 = lane * 8;
        const float* wr = Wsa + (size_t)k * 512 + n0;
        float4 w0 = *(const float4*)wr, w1 = *(const float4*)(wr + 4);
        float4 l0 = *(const float4*)(a_sa + n0), l1 = *(const float4*)(a_sa + n0 + 4);
        float4 r0 = *(const float4*)(a_sa + 512 + n0), r1 = *(const float4*)(a_sa + 512 + n0 + 4);
        float sl_ = w0.x*l0.x + w0.y*l0.y + w0.z*l0.z + w0.w*l0.w
                  + w1.x*l1.x + w1.y*l1.y + w1.z*l1.z + w1.w*l1.w;
        float sr_ = w0.x*r0.x + w0.y*r0.y + w0.z*r0.z + w0.w*r0.w
                  + w1.x*r1.x + w1.y*r1.y + w1.z*r1.z + w1.w*r1.w;
#pragma unroll
        for (int off = 32; off; off >>= 1) { sl_ += __shfl_down(sl_, off); sr_ += __shfl_down(sr_, off); }
        if (lane == 0) { wsl[k] = sl_; wsr[k] = sr_; }
    }
}

// ===== d2: k_fused — {nt grid-stride scan -> ballot masks} + {MFMA GEMM} + {projections} =====
// blocks [0,7680): bid%5<4 -> scan; bid%5==4 -> GEMM. blocks [7680,9216): projections.
__global__ __launch_bounds__(256) void k_fused(const float* __restrict__ x,
                                               const bf16_t* __restrict__ wt,
                                               const float* __restrict__ adjA,
                                               const float* __restrict__ adjB,
                                               const float* __restrict__ Wa,
                                               const float* __restrict__ Wb,
                                               const float* __restrict__ wsl,
                                               const float* __restrict__ wsr,
                                               unsigned long long* __restrict__ maskw,
                                               unsigned short* __restrict__ h,
                                               unsigned short* __restrict__ g,
                                               float* __restrict__ xal, float* __restrict__ xar,
                                               float* __restrict__ xbl, float* __restrict__ xbr,
                                               float* __restrict__ sl, float* __restrict__ sr) {
    int bid = blockIdx.x;
    int wave = threadIdx.x >> 6, lane = threadIdx.x & 63;
    if (bid < 7680) {
        int grp = bid % 5;
        if (grp < 4) {
            // ---- nt scan: flat grid-stride, 64-u4 chunks, 4 ballots -> mask words ----
            int sblk = (bid / 5) * 4 + grp;          // 0..6143
            int gt = sblk * 256 + threadIdx.x;       // 0..SCAN_T-1
            int wb0 = gt - lane;                     // wave base (multiple of 64)
            const u32x4* a4 = (const u32x4*)adjA;
            const u32x4* b4 = (const u32x4*)adjB;
#pragma unroll
            for (int j = 0; j < 12; j++) {
                int f = gt + j * SCAN_T;             // flat uint4 index, < 2*HALF_U4
                u32x4 v;
                if (f < HALF_U4) v = __builtin_nontemporal_load(a4 + f);   // wave-uniform branch
                else             v = __builtin_nontemporal_load(b4 + (f - HALF_U4));
                unsigned long long b0 = __ballot(v[0] != 0u);
                unsigned long long b1 = __ballot(v[1] != 0u);
                unsigned long long b2 = __ballot(v[2] != 0u);
                unsigned long long b3 = __ballot(v[3] != 0u);
                int seg = (wb0 + j * SCAN_T) >> 6;   // 0..294911
                if (lane < 4) {
                    unsigned long long bb = (lane == 0) ? b0 : (lane == 1) ? b1
                                          : (lane == 2) ? b2 : b3;
                    maskw[(size_t)seg * 4 + lane] = bb;
                }
            }
        } else {
            // ---- GEMM tile: 64 rows x 64 cols, MFMA 16x16x32, A cvt in-register ----
            int tt = bid / 5;                        // 0..1535
            int row0 = (tt % (NN / 64)) * 64 + wave * 16;
            int col0 = (tt / (NN / 64)) * 64;
            int lr = lane & 15;
            int kg = (lane >> 4) * 8;

            f32x4 acc[4] = {{0,0,0,0},{0,0,0,0},{0,0,0,0},{0,0,0,0}};
            const float* ap = x + (size_t)(row0 + lr) * DD + kg;
            const bf16_t* bp = wt + (size_t)(col0 + lr) * DD + kg;

            for (int k0 = 0; k0 < DD; k0 += 32) {
                float4 a0 = *(const float4*)(ap + k0);
                float4 a1 = *(const float4*)(ap + k0 + 4);
                u16x8 au;
                au[0] = f2bf(a0.x); au[1] = f2bf(a0.y); au[2] = f2bf(a0.z); au[3] = f2bf(a0.w);
                au[4] = f2bf(a1.x); au[5] = f2bf(a1.y); au[6] = f2bf(a1.z); au[7] = f2bf(a1.w);
                bf16x8 a = __builtin_bit_cast(bf16x8, au);
#pragma unroll
                for (int n = 0; n < 4; n++) {
                    bf16x8 b = *(const bf16x8*)(bp + (size_t)n * 16 * DD + k0);
                    acc[n] = __builtin_amdgcn_mfma_f32_16x16x32_bf16(a, b, acc[n], 0, 0, 0);
                }
            }
            int dcol = lane & 15;
            int dr0 = (lane >> 4) * 4;
#pragma unroll
            for (int n = 0; n < 4; n++) {
                int col = col0 + n * 16 + dcol;
                unsigned short* dst = (col < 512) ? h : g;
                int cc = col & 511;
#pragma unroll
                for (int rr = 0; rr < 4; rr++) {
                    int mr = row0 + dr0 + rr;
                    dst[(size_t)mr * 512 + cc] = f2bf(acc[n][rr]);
                }
            }
        }
    } else {
        // ---- projections: rows pid*4+wave; 6 dot products vs x-row ----
        int pid = bid - 7680;                        // 0..1535
        int row = pid * 4 + wave;
        int k0 = lane * 8;
        const float* xr_ = x + (size_t)row * DD + k0;
        float4 v0 = *(const float4*)xr_;
        float4 v1 = *(const float4*)(xr_ + 4);
        float xv[8] = {v0.x, v0.y, v0.z, v0.w, v1.x, v1.y, v1.z, v1.w};
        float d[6] = {0, 0, 0, 0, 0, 0};
        const float* srcs[6] = {Wa + k0, Wa + 512 + k0, Wb + k0, Wb + 512 + k0, wsl + k0, wsr + k0};
#pragma unroll
        for (int q = 0; q < 6; q++) {
            float4 w0 = *(const float4*)srcs[q];
            float4 w1 = *(const float4*)(srcs[q] + 4);
            float wv[8] = {w0.x, w0.y, w0.z, w0.w, w1.x, w1.y, w1.z, w1.w};
#pragma unroll
            for (int j = 0; j < 8; j++) d[q] += xv[j] * wv[j];
        }
#pragma unroll
        for (int off = 32; off; off >>= 1)
#pragma unroll
            for (int q = 0; q < 6; q++) d[q] += __shfl_down(d[q], off);
        if (lane == 0) {
            xal[row] = d[0]; xar[row] = d[1];
            xbl[row] = d[2]; xbr[row] = d[3];
            sl[row] = d[4]; sr[row] = d[5];
        }
    }
}

// ===== d3: k_final — mask extraction + gates + attention normalize + gathers + epilogue =====
// Row i's masks: 96 words at maskw[row96 * 96], word W = seg*4+q (seg=W>>2, q=W&3),
// bit l of word W -> col = seg*256 + l*4 + q.
__global__ __launch_bounds__(256) void k_final(
    const unsigned long long* __restrict__ maskw,
    const unsigned short* __restrict__ h, const unsigned short* __restrict__ g,
    const float* __restrict__ sl, const float* __restrict__ sr,
    const float* __restrict__ xal, const float* __restrict__ xar,
    const float* __restrict__ xbl, const float* __restrict__ xbr,
    const float* __restrict__ ba, const float* __restrict__ bb,
    const float* __restrict__ bias, float* __restrict__ out) {
    int i = blockIdx.x;
    int tid = threadIdx.x;
    int wave = tid >> 6, lane = tid & 63;
    __shared__ float w[CAP];
    __shared__ int ja[CAP], jb[CAP];
    __shared__ int tot[4];
    __shared__ float s_denom, s_ga, s_gb;

    // waves 0,1 = A words 0-47 / 48-95; waves 2,3 = B words 0-47 / 48-95
    int whalf = wave & 1;
    size_t rowbase = (size_t)((wave < 2) ? i : (NN + i)) * 96;
    int widx = whalf * 48 + lane;                 // 0..95 (lanes 48..63 idle)
    unsigned long long m = (lane < 48) ? maskw[rowbase + widx] : 0ull;
    int c = __popcll(m);
    int p = c;
#pragma unroll
    for (int off = 1; off < 64; off <<= 1) {
        int t = __shfl_up(p, off);
        if (lane >= off) p += t;
    }
    if (lane == 63) tot[wave] = p;
    __syncthreads();
    int base = (wave == 1) ? tot[0] : (wave == 3) ? tot[2] : 0;
    int pos = base + p - c;
    int* dst = (wave < 2) ? ja : jb;
    while (m) {
        int b = __ffsll((long long)m) - 1;
        m &= m - 1;
        int col = (widx >> 2) * 256 + b * 4 + (widx & 3);
        if (pos < CAP) dst[pos] = col;
        pos++;
    }
    __syncthreads();
    int cA = tot[0] + tot[1]; cA = cA > CAP ? CAP : cA;
    int cB = tot[2] + tot[3]; cB = cB > CAP ? CAP : cB;

    // ---- attention weights ----
    if (tid < cA) {
        int j = ja[tid];
        float s = sl[i] + sr[j];
        float lrelu = s > 0.f ? s : 0.01f * s;
        w[tid] = expf(-lrelu);
    }
    __syncthreads();

    if (tid < 64) {
        float p2 = 0.f, gasum = 0.f, gbsum = 0.f;
        for (int t = tid; t < cA; t += 64) { p2 += w[t]; gasum += xal[ja[t]]; }
        for (int t = tid; t < cB; t += 64) gbsum += xbl[jb[t]];
#pragma unroll
        for (int off = 32; off; off >>= 1) {
            p2 += __shfl_down(p2, off);
            gasum += __shfl_down(gasum, off);
            gbsum += __shfl_down(gbsum, off);
        }
        if (tid == 0) {
            s_denom = p2;
            s_ga = sigmoidf_(gasum + xar[i] + ba[0]);
            s_gb = sigmoidf_(gbsum + xbr[i] + bb[0]);
        }
    }
    __syncthreads();
    float inv = 1.f / (s_denom + 1e-5f);
    float ga = s_ga, gb = s_gb;

    int d0 = tid * 2;
    float a0 = 0, a1 = 0, b0 = 0, b1 = 0;
#pragma unroll 4
    for (int t = 0; t < cA; t++) {
        unsigned hv = *(const unsigned*)(h + (size_t)ja[t] * 512 + d0);
        float wt_ = w[t];
        a0 += wt_ * bf2f((unsigned short)(hv & 0xffff));
        a1 += wt_ * bf2f((unsigned short)(hv >> 16));
    }
#pragma unroll 4
    for (int t = 0; t < cB; t++) {
        unsigned gv = *(const unsigned*)(g + (size_t)jb[t] * 512 + d0);
        b0 += bf2f((unsigned short)(gv & 0xffff));
        b1 += bf2f((unsigned short)(gv >> 16));
    }
    float z0 = ga * (a0 * inv) + gb * (b0 + bias[d0]);
    float z1 = ga * (a1 * inv) + gb * (b1 + bias[d0 + 1]);
    out[(size_t)i * 512 + d0]     = sigmoidf_(z0);
    out[(size_t)i * 512 + d0 + 1] = sigmoidf_(z1);
}

extern "C" void kernel_launch(void* const* d_in, const int* in_sizes, int n_in,
                              void* d_out, int out_size, void* d_ws, size_t ws_size,
                              hipStream_t stream) {
    const float* x    = (const float*)d_in[0];
    const float* adjA = (const float*)d_in[1];
    const float* adjB = (const float*)d_in[2];
    const float* Wsa  = (const float*)d_in[3];
    const float* a_sa = (const float*)d_in[4];
    const float* Wg   = (const float*)d_in[5];
    const float* bg   = (const float*)d_in[6];
    const float* Wa   = (const float*)d_in[7];
    const float* ba   = (const float*)d_in[8];
    const float* Wb   = (const float*)d_in[9];
    const float* bb   = (const float*)d_in[10];
    float* out = (float*)d_out;

    char* ws = (char*)d_ws;
    size_t off = 0;
    auto alloc = [&](size_t bytes) -> void* {
        void* p = ws + off;
        off += (bytes + 255) & ~(size_t)255;
        return p;
    };
    unsigned short* wt = (unsigned short*)alloc((size_t)1024 * DD * 2);
    unsigned short* h  = (unsigned short*)alloc((size_t)NN * DD * 2);
    unsigned short* g  = (unsigned short*)alloc((size_t)NN * DD * 2);
    unsigned long long* maskw = (unsigned long long*)alloc((size_t)294912 * 4 * 8);
    float* xal = (float*)alloc((size_t)NN * 4);
    float* xar = (float*)alloc((size_t)NN * 4);
    float* xbl = (float*)alloc((size_t)NN * 4);
    float* xbr = (float*)alloc((size_t)NN * 4);
    float* sl  = (float*)alloc((size_t)NN * 4);
    float* sr  = (float*)alloc((size_t)NN * 4);
    float* wsl = (float*)alloc((size_t)DD * 4);
    float* wsr = (float*)alloc((size_t)DD * 4);

    // d1: W^T (bf16) + w_sl/w_sr
    k_prep<<<256, 256, 0, stream>>>(Wsa, Wg, a_sa, wt, wsl, wsr);
    // d2: nt grid-stride scan + GEMM + projections
    k_fused<<<9216, 256, 0, stream>>>(x, (const bf16_t*)wt, adjA, adjB, Wa, Wb, wsl, wsr,
                                      maskw, h, g, xal, xar, xbl, xbr, sl, sr);
    // d3: extraction + gates + attention + gathers + epilogue
    k_final<<<NN, 256, 0, stream>>>(maskw, h, g, sl, sr, xal, xar, xbl, xbr,
                                    ba, bb, bg, out);
}

// Round 9
// 170.378 us; speedup vs baseline: 1.0376x; 1.0341x over previous
//
#include <hip/hip_runtime.h>
#include <math.h>

#define NN 6144
#define DD 512
#define CAP 128
#define NWAVES 24576                   // scan waves
#define SEGS_PER_MAT 147456            // (NN*NN/4)/64 1KB-chunks per adjacency
#define DEPTH 12                       // gload_lds pipeline depth per wave

typedef __bf16 bf16_t;
typedef __bf16 bf16x8 __attribute__((ext_vector_type(8)));
typedef unsigned short u16x8 __attribute__((ext_vector_type(8)));
typedef float f32x4 __attribute__((ext_vector_type(4)));
typedef unsigned u32x4 __attribute__((ext_vector_type(4)));

__device__ __forceinline__ float bf2f(unsigned short u) {
    unsigned v = ((unsigned)u) << 16;
    return __builtin_bit_cast(float, v);
}
__device__ __forceinline__ unsigned short f2bf(float f) {
    unsigned u = __builtin_bit_cast(unsigned, f);
    u += 0x7fffu + ((u >> 16) & 1u);   // round-to-nearest-even
    return (unsigned short)(u >> 16);
}
__device__ __forceinline__ float sigmoidf_(float z) { return 1.0f / (1.0f + expf(-z)); }

// async global->LDS, 16B per lane; lds dst must be wave-uniform (HW adds lane*16)
__device__ __forceinline__ void gl_lds16(const void* gsrc, void* ldst) {
    __builtin_amdgcn_global_load_lds(
        (const __attribute__((address_space(1))) unsigned*)gsrc,
        (__attribute__((address_space(3))) unsigned*)ldst, 16, 0, 0);
}

// =========== d1: k_prep — wt transpose (blocks 0..127) + w_sl/w_sr (blocks 128..255) ===========
__global__ __launch_bounds__(256) void k_prep(const float* __restrict__ Wsa,
                                              const float* __restrict__ Wg,
                                              const float* __restrict__ a_sa,
                                              unsigned short* __restrict__ wt,
                                              float* __restrict__ wsl, float* __restrict__ wsr) {
    __shared__ float s[64][65];
    int bid = blockIdx.x;
    int wave = threadIdx.x >> 6, lane = threadIdx.x & 63;
    if (bid < 128) {
        int n0 = (bid & 15) * 64;
        int k0 = (bid >> 4) * 64;
        int tx = threadIdx.x & 63, ty = threadIdx.x >> 6;
        const float* src = (n0 < 512) ? Wsa : Wg;
        int nn0 = n0 & 511;
#pragma unroll
        for (int kk = 0; kk < 64; kk += 4)
            s[kk + ty][tx] = src[(size_t)(k0 + kk + ty) * 512 + nn0 + tx];
        __syncthreads();
#pragma unroll
        for (int nn = 0; nn < 64; nn += 4)
            wt[(size_t)(n0 + nn + ty) * 512 + k0 + tx] = f2bf(s[tx][nn + ty]);
    } else {
        int k = (bid - 128) * 4 + wave;         // 0..511
        int n0 = lane * 8;
        const float* wr = Wsa + (size_t)k * 512 + n0;
        float4 w0 = *(const float4*)wr, w1 = *(const float4*)(wr + 4);
        float4 l0 = *(const float4*)(a_sa + n0), l1 = *(const float4*)(a_sa + n0 + 4);
        float4 r0 = *(const float4*)(a_sa + 512 + n0), r1 = *(const float4*)(a_sa + 512 + n0 + 4);
        float sl_ = w0.x*l0.x + w0.y*l0.y + w0.z*l0.z + w0.w*l0.w
                  + w1.x*l1.x + w1.y*l1.y + w1.z*l1.z + w1.w*l1.w;
        float sr_ = w0.x*r0.x + w0.y*r0.y + w0.z*r0.z + w0.w*r0.w
                  + w1.x*r1.x + w1.y*r1.y + w1.z*r1.z + w1.w*r1.w;
#pragma unroll
        for (int off = 32; off; off >>= 1) { sl_ += __shfl_down(sl_, off); sr_ += __shfl_down(sr_, off); }
        if (lane == 0) { wsl[k] = sl_; wsr[k] = sr_; }
    }
}

// ===== d2: k_fused — {12-deep gload_lds scan -> ballot masks} + {MFMA GEMM} + {projections} =====
// blocks [0,7680): bid%5<4 -> scan; bid%5==4 -> GEMM. blocks [7680,9216): projections.
__global__ __launch_bounds__(256) void k_fused(const float* __restrict__ x,
                                               const bf16_t* __restrict__ wt,
                                               const float* __restrict__ adjA,
                                               const float* __restrict__ adjB,
                                               const float* __restrict__ Wa,
                                               const float* __restrict__ Wb,
                                               const float* __restrict__ wsl,
                                               const float* __restrict__ wsr,
                                               unsigned long long* __restrict__ maskw,
                                               unsigned short* __restrict__ h,
                                               unsigned short* __restrict__ g,
                                               float* __restrict__ xal, float* __restrict__ xar,
                                               float* __restrict__ xbl, float* __restrict__ xbr,
                                               float* __restrict__ sl, float* __restrict__ sr) {
    __shared__ __align__(16) unsigned char lds[4][DEPTH][1024];   // per-wave private slots
    int bid = blockIdx.x;
    int wave = threadIdx.x >> 6, lane = threadIdx.x & 63;
    if (bid < 7680) {
        int grp = bid % 5;
        if (grp < 4) {
            // ---- scan: one wave = 12 grid-strided 1KB chunks, all in flight via gload_lds ----
            int sblk = (bid / 5) * 4 + grp;          // 0..6143
            int gw = sblk * 4 + wave;                // 0..24575
            const char* baseA = (const char*)adjA;
            const char* baseB = (const char*)adjB;
            // issue all 12 (chunks 0..5 in A, 6..11 in B — compile-time split)
#pragma unroll
            for (int j = 0; j < 6; j++) {
                size_t boff = ((size_t)(gw + j * NWAVES) * 64 + lane) * 16;
                gl_lds16(baseA + boff, &lds[wave][j][0]);
            }
#pragma unroll
            for (int j = 6; j < 12; j++) {
                size_t boff = ((size_t)(gw + j * NWAVES - SEGS_PER_MAT) * 64 + lane) * 16;
                gl_lds16(baseB + boff, &lds[wave][j][0]);
            }
            asm volatile("s_waitcnt vmcnt(0)" ::: "memory");
            __builtin_amdgcn_sched_barrier(0);
            unsigned long long myw = 0;
#pragma unroll
            for (int j = 0; j < 12; j++) {
                u32x4 v = *(const u32x4*)&lds[wave][j][lane * 16];
                unsigned long long b0 = __ballot(v[0] != 0u);
                unsigned long long b1 = __ballot(v[1] != 0u);
                unsigned long long b2 = __ballot(v[2] != 0u);
                unsigned long long b3 = __ballot(v[3] != 0u);
                if ((lane >> 2) == j) {
                    int q = lane & 3;
                    myw = (q == 0) ? b0 : (q == 1) ? b1 : (q == 2) ? b2 : b3;
                }
            }
            if (lane < 48) {
                size_t seg = (size_t)gw + (size_t)(lane >> 2) * NWAVES;
                maskw[seg * 4 + (lane & 3)] = myw;
            }
        } else {
            // ---- GEMM tile: 64 rows x 64 cols, MFMA 16x16x32, A cvt in-register ----
            int tt = bid / 5;                        // 0..1535
            int row0 = (tt % (NN / 64)) * 64 + wave * 16;
            int col0 = (tt / (NN / 64)) * 64;
            int lr = lane & 15;
            int kg = (lane >> 4) * 8;

            f32x4 acc[4] = {{0,0,0,0},{0,0,0,0},{0,0,0,0},{0,0,0,0}};
            const float* ap = x + (size_t)(row0 + lr) * DD + kg;
            const bf16_t* bp = wt + (size_t)(col0 + lr) * DD + kg;

            for (int k0 = 0; k0 < DD; k0 += 32) {
                float4 a0 = *(const float4*)(ap + k0);
                float4 a1 = *(const float4*)(ap + k0 + 4);
                u16x8 au;
                au[0] = f2bf(a0.x); au[1] = f2bf(a0.y); au[2] = f2bf(a0.z); au[3] = f2bf(a0.w);
                au[4] = f2bf(a1.x); au[5] = f2bf(a1.y); au[6] = f2bf(a1.z); au[7] = f2bf(a1.w);
                bf16x8 a = __builtin_bit_cast(bf16x8, au);
#pragma unroll
                for (int n = 0; n < 4; n++) {
                    bf16x8 b = *(const bf16x8*)(bp + (size_t)n * 16 * DD + k0);
                    acc[n] = __builtin_amdgcn_mfma_f32_16x16x32_bf16(a, b, acc[n], 0, 0, 0);
                }
            }
            int dcol = lane & 15;
            int dr0 = (lane >> 4) * 4;
#pragma unroll
            for (int n = 0; n < 4; n++) {
                int col = col0 + n * 16 + dcol;
                unsigned short* dst = (col < 512) ? h : g;
                int cc = col & 511;
#pragma unroll
                for (int rr = 0; rr < 4; rr++) {
                    int mr = row0 + dr0 + rr;
                    dst[(size_t)mr * 512 + cc] = f2bf(acc[n][rr]);
                }
            }
        }
    } else {
        // ---- projections: rows pid*4+wave; 6 dot products vs x-row ----
        int pid = bid - 7680;                        // 0..1535
        int row = pid * 4 + wave;
        int k0 = lane * 8;
        const float* xr_ = x + (size_t)row * DD + k0;
        float4 v0 = *(const float4*)xr_;
        float4 v1 = *(const float4*)(xr_ + 4);
        float xv[8] = {v0.x, v0.y, v0.z, v0.w, v1.x, v1.y, v1.z, v1.w};
        float d[6] = {0, 0, 0, 0, 0, 0};
        const float* srcs[6] = {Wa + k0, Wa + 512 + k0, Wb + k0, Wb + 512 + k0, wsl + k0, wsr + k0};
#pragma unroll
        for (int q = 0; q < 6; q++) {
            float4 w0 = *(const float4*)srcs[q];
            float4 w1 = *(const float4*)(srcs[q] + 4);
            float wv[8] = {w0.x, w0.y, w0.z, w0.w, w1.x, w1.y, w1.z, w1.w};
#pragma unroll
            for (int j = 0; j < 8; j++) d[q] += xv[j] * wv[j];
        }
#pragma unroll
        for (int off = 32; off; off >>= 1)
#pragma unroll
            for (int q = 0; q < 6; q++) d[q] += __shfl_down(d[q], off);
        if (lane == 0) {
            xal[row] = d[0]; xar[row] = d[1];
            xbl[row] = d[2]; xbr[row] = d[3];
            sl[row] = d[4]; sr[row] = d[5];
        }
    }
}

// ===== d3: k_final — mask extraction + gates + attention normalize + gathers + epilogue =====
// Row i's masks: 96 words at maskw[row * 96], word W = seg*4+q; bit l of word W -> col = seg*256 + l*4 + q.
__global__ __launch_bounds__(256) void k_final(
    const unsigned long long* __restrict__ maskw,
    const unsigned short* __restrict__ h, const unsigned short* __restrict__ g,
    const float* __restrict__ sl, const float* __restrict__ sr,
    const float* __restrict__ xal, const float* __restrict__ xar,
    const float* __restrict__ xbl, const float* __restrict__ xbr,
    const float* __restrict__ ba, const float* __restrict__ bb,
    const float* __restrict__ bias, float* __restrict__ out) {
    int i = blockIdx.x;
    int tid = threadIdx.x;
    int wave = tid >> 6, lane = tid & 63;
    __shared__ float w[CAP];
    __shared__ int ja[CAP], jb[CAP];
    __shared__ int tot[4];
    __shared__ float s_denom, s_ga, s_gb;

    // waves 0,1 = A words 0-47 / 48-95; waves 2,3 = B words 0-47 / 48-95
    int whalf = wave & 1;
    size_t rowbase = (size_t)((wave < 2) ? i : (NN + i)) * 96;
    int widx = whalf * 48 + lane;                 // 0..95 (lanes 48..63 idle)
    unsigned long long m = (lane < 48) ? maskw[rowbase + widx] : 0ull;
    int c = __popcll(m);
    int p = c;
#pragma unroll
    for (int off = 1; off < 64; off <<= 1) {
        int t = __shfl_up(p, off);
        if (lane >= off) p += t;
    }
    if (lane == 63) tot[wave] = p;
    __syncthreads();
    int base = (wave == 1) ? tot[0] : (wave == 3) ? tot[2] : 0;
    int pos = base + p - c;
    int* dst = (wave < 2) ? ja : jb;
    while (m) {
        int b = __ffsll((long long)m) - 1;
        m &= m - 1;
        int col = (widx >> 2) * 256 + b * 4 + (widx & 3);
        if (pos < CAP) dst[pos] = col;
        pos++;
    }
    __syncthreads();
    int cA = tot[0] + tot[1]; cA = cA > CAP ? CAP : cA;
    int cB = tot[2] + tot[3]; cB = cB > CAP ? CAP : cB;

    // ---- attention weights ----
    if (tid < cA) {
        int j = ja[tid];
        float s = sl[i] + sr[j];
        float lrelu = s > 0.f ? s : 0.01f * s;
        w[tid] = expf(-lrelu);
    }
    __syncthreads();

    if (tid < 64) {
        float p2 = 0.f, gasum = 0.f, gbsum = 0.f;
        for (int t = tid; t < cA; t += 64) { p2 += w[t]; gasum += xal[ja[t]]; }
        for (int t = tid; t < cB; t += 64) gbsum += xbl[jb[t]];
#pragma unroll
        for (int off = 32; off; off >>= 1) {
            p2 += __shfl_down(p2, off);
            gasum += __shfl_down(gasum, off);
            gbsum += __shfl_down(gbsum, off);
        }
        if (tid == 0) {
            s_denom = p2;
            s_ga = sigmoidf_(gasum + xar[i] + ba[0]);
            s_gb = sigmoidf_(gbsum + xbr[i] + bb[0]);
        }
    }
    __syncthreads();
    float inv = 1.f / (s_denom + 1e-5f);
    float ga = s_ga, gb = s_gb;

    int d0 = tid * 2;
    float a0 = 0, a1 = 0, b0 = 0, b1 = 0;
#pragma unroll 4
    for (int t = 0; t < cA; t++) {
        unsigned hv = *(const unsigned*)(h + (size_t)ja[t] * 512 + d0);
        float wt_ = w[t];
        a0 += wt_ * bf2f((unsigned short)(hv & 0xffff));
        a1 += wt_ * bf2f((unsigned short)(hv >> 16));
    }
#pragma unroll 4
    for (int t = 0; t < cB; t++) {
        unsigned gv = *(const unsigned*)(g + (size_t)jb[t] * 512 + d0);
        b0 += bf2f((unsigned short)(gv & 0xffff));
        b1 += bf2f((unsigned short)(gv >> 16));
    }
    float z0 = ga * (a0 * inv) + gb * (b0 + bias[d0]);
    float z1 = ga * (a1 * inv) + gb * (b1 + bias[d0 + 1]);
    out[(size_t)i * 512 + d0]     = sigmoidf_(z0);
    out[(size_t)i * 512 + d0 + 1] = sigmoidf_(z1);
}

extern "C" void kernel_launch(void* const* d_in, const int* in_sizes, int n_in,
                              void* d_out, int out_size, void* d_ws, size_t ws_size,
                              hipStream_t stream) {
    const float* x    = (const float*)d_in[0];
    const float* adjA = (const float*)d_in[1];
    const float* adjB = (const float*)d_in[2];
    const float* Wsa  = (const float*)d_in[3];
    const float* a_sa = (const float*)d_in[4];
    const float* Wg   = (const float*)d_in[5];
    const float* bg   = (const float*)d_in[6];
    const float* Wa   = (const float*)d_in[7];
    const float* ba   = (const float*)d_in[8];
    const float* Wb   = (const float*)d_in[9];
    const float* bb   = (const float*)d_in[10];
    float* out = (float*)d_out;

    char* ws = (char*)d_ws;
    size_t off = 0;
    auto alloc = [&](size_t bytes) -> void* {
        void* p = ws + off;
        off += (bytes + 255) & ~(size_t)255;
        return p;
    };
    unsigned short* wt = (unsigned short*)alloc((size_t)1024 * DD * 2);
    unsigned short* h  = (unsigned short*)alloc((size_t)NN * DD * 2);
    unsigned short* g  = (unsigned short*)alloc((size_t)NN * DD * 2);
    unsigned long long* maskw = (unsigned long long*)alloc((size_t)294912 * 4 * 8);
    float* xal = (float*)alloc((size_t)NN * 4);
    float* xar = (float*)alloc((size_t)NN * 4);
    float* xbl = (float*)alloc((size_t)NN * 4);
    float* xbr = (float*)alloc((size_t)NN * 4);
    float* sl  = (float*)alloc((size_t)NN * 4);
    float* sr  = (float*)alloc((size_t)NN * 4);
    float* wsl = (float*)alloc((size_t)DD * 4);
    float* wsr = (float*)alloc((size_t)DD * 4);

    // d1: W^T (bf16) + w_sl/w_sr
    k_prep<<<256, 256, 0, stream>>>(Wsa, Wg, a_sa, wt, wsl, wsr);
    // d2: 12-deep gload_lds scan + GEMM + projections
    k_fused<<<9216, 256, 0, stream>>>(x, (const bf16_t*)wt, adjA, adjB, Wa, Wb, wsl, wsr,
                                      maskw, h, g, xal, xar, xbl, xbr, sl, sr);
    // d3: extraction + gates + attention + gathers + epilogue
    k_final<<<NN, 256, 0, stream>>>(maskw, h, g, sl, sr, xal, xar, xbl, xbr,
                                    ba, bb, bg, out);
}

// Round 10
// 164.795 us; speedup vs baseline: 1.0727x; 1.0339x over previous
//
#include <hip/hip_runtime.h>
#include <math.h>

#define NN 6144
#define DD 512
#define CAP 128

typedef __bf16 bf16_t;
typedef __bf16 bf16x8 __attribute__((ext_vector_type(8)));
typedef unsigned short u16x8 __attribute__((ext_vector_type(8)));
typedef float f32x4 __attribute__((ext_vector_type(4)));
typedef unsigned u32x4 __attribute__((ext_vector_type(4)));

__device__ __forceinline__ float bf2f(unsigned short u) {
    unsigned v = ((unsigned)u) << 16;
    return __builtin_bit_cast(float, v);
}
__device__ __forceinline__ unsigned short f2bf(float f) {
    unsigned u = __builtin_bit_cast(unsigned, f);
    u += 0x7fffu + ((u >> 16) & 1u);   // round-to-nearest-even
    return (unsigned short)(u >> 16);
}
__device__ __forceinline__ float sigmoidf_(float z) { return 1.0f / (1.0f + expf(-z)); }

// =========== d1: k_prep — wt transpose (blocks 0..127) + w_sl/w_sr (blocks 128..255) ===========
__global__ __launch_bounds__(256) void k_prep(const float* __restrict__ Wsa,
                                              const float* __restrict__ Wg,
                                              const float* __restrict__ a_sa,
                                              unsigned short* __restrict__ wt,
                                              float* __restrict__ wsl, float* __restrict__ wsr) {
    __shared__ float s[64][65];
    int bid = blockIdx.x;
    int wave = threadIdx.x >> 6, lane = threadIdx.x & 63;
    if (bid < 128) {
        int n0 = (bid & 15) * 64;
        int k0 = (bid >> 4) * 64;
        int tx = threadIdx.x & 63, ty = threadIdx.x >> 6;
        const float* src = (n0 < 512) ? Wsa : Wg;
        int nn0 = n0 & 511;
#pragma unroll
        for (int kk = 0; kk < 64; kk += 4)
            s[kk + ty][tx] = src[(size_t)(k0 + kk + ty) * 512 + nn0 + tx];
        __syncthreads();
#pragma unroll
        for (int nn = 0; nn < 64; nn += 4)
            wt[(size_t)(n0 + nn + ty) * 512 + k0 + tx] = f2bf(s[tx][nn + ty]);
    } else {
        int k = (bid - 128) * 4 + wave;         // 0..511
        int n0 = lane * 8;
        const float* wr = Wsa + (size_t)k * 512 + n0;
        float4 w0 = *(const float4*)wr, w1 = *(const float4*)(wr + 4);
        float4 l0 = *(const float4*)(a_sa + n0), l1 = *(const float4*)(a_sa + n0 + 4);
        float4 r0 = *(const float4*)(a_sa + 512 + n0), r1 = *(const float4*)(a_sa + 512 + n0 + 4);
        float sl_ = w0.x*l0.x + w0.y*l0.y + w0.z*l0.z + w0.w*l0.w
                  + w1.x*l1.x + w1.y*l1.y + w1.z*l1.z + w1.w*l1.w;
        float sr_ = w0.x*r0.x + w0.y*r0.y + w0.z*r0.z + w0.w*r0.w
                  + w1.x*r1.x + w1.y*r1.y + w1.z*r1.z + w1.w*r1.w;
#pragma unroll
        for (int off = 32; off; off >>= 1) { sl_ += __shfl_down(sl_, off); sr_ += __shfl_down(sr_, off); }
        if (lane == 0) { wsl[k] = sl_; wsr[k] = sr_; }
    }
}

// ===== d2: k_fused — {nt row-scan -> compact idx} + {MFMA GEMM} + {projections} =====
// blocks [0,4608): bid%3<2 -> scan (4 waves x 1 row);  bid%3==2 -> GEMM tile.
// blocks [4608,6144): per-row 6-dot projections.
__global__ __launch_bounds__(256) void k_fused(const float* __restrict__ x,
                                               const bf16_t* __restrict__ wt,
                                               const float* __restrict__ adjA,
                                               const float* __restrict__ adjB,
                                               const float* __restrict__ Wa,
                                               const float* __restrict__ Wb,
                                               const float* __restrict__ wsl,
                                               const float* __restrict__ wsr,
                                               int* __restrict__ idxA, int* __restrict__ idxB,
                                               int* __restrict__ cntA, int* __restrict__ cntB,
                                               unsigned short* __restrict__ h,
                                               unsigned short* __restrict__ g,
                                               float* __restrict__ xal, float* __restrict__ xar,
                                               float* __restrict__ xbl, float* __restrict__ xbr,
                                               float* __restrict__ sl, float* __restrict__ sr) {
    int bid = blockIdx.x;
    int wave = threadIdx.x >> 6, lane = threadIdx.x & 63;
    if (bid < 4608) {
        int grp = bid % 3;
        if (grp < 2) {
            // ---- scan: one wave = one adjacency row, 24 nt loads, prefix-compact ----
            int sid = (bid / 3) * 2 + grp;          // 0..3071
            int row = sid * 4 + wave;               // 0..12287
            int which = row >= NN;
            int r = which ? row - NN : row;
            const float* adj = which ? adjB : adjA;
            int* idx = (which ? idxB : idxA) + (size_t)r * CAP;
            int* cnt = which ? cntB : cntA;

            const u32x4* arow = (const u32x4*)(adj + (size_t)r * NN) + lane;
            u32x4 v[24];
#pragma unroll
            for (int j = 0; j < 24; j++) v[j] = __builtin_nontemporal_load(arow + j * 64);

            unsigned m[3] = {0, 0, 0};
#pragma unroll
            for (int j = 0; j < 24; j++) {
                unsigned w_ = (j >> 3);
                unsigned sh = (j & 7) * 4;
                m[w_] |= (v[j][0] != 0u ? 1u : 0u) << sh;
                m[w_] |= (v[j][1] != 0u ? 1u : 0u) << (sh + 1);
                m[w_] |= (v[j][2] != 0u ? 1u : 0u) << (sh + 2);
                m[w_] |= (v[j][3] != 0u ? 1u : 0u) << (sh + 3);
            }
            int c = __popc(m[0]) + __popc(m[1]) + __popc(m[2]);
            int p = c;
#pragma unroll
            for (int off = 1; off < 64; off <<= 1) {
                int t = __shfl_up(p, off);
                if (lane >= off) p += t;
            }
            int pos = p - c;                 // exclusive prefix
            int total = __shfl(p, 63);
#pragma unroll
            for (int w_ = 0; w_ < 3; w_++) {
                unsigned mm = m[w_];
                while (mm) {
                    int b = __ffs(mm) - 1;
                    mm &= mm - 1;
                    int e = w_ * 32 + b;               // element 0..95 within lane
                    int col = (e >> 2) * 256 + lane * 4 + (e & 3);
                    if (pos < CAP) idx[pos] = col;
                    pos++;
                }
            }
            if (lane == 0) cnt[r] = total > CAP ? CAP : total;
        } else {
            // ---- GEMM tile: 64 rows x 64 cols, MFMA 16x16x32, A cvt in-register ----
            int tt = bid / 3;                        // 0..1535
            int row0 = (tt % (NN / 64)) * 64 + wave * 16;
            int col0 = (tt / (NN / 64)) * 64;
            int lr = lane & 15;
            int kg = (lane >> 4) * 8;

            f32x4 acc[4] = {{0,0,0,0},{0,0,0,0},{0,0,0,0},{0,0,0,0}};
            const float* ap = x + (size_t)(row0 + lr) * DD + kg;
            const bf16_t* bp = wt + (size_t)(col0 + lr) * DD + kg;

            for (int k0 = 0; k0 < DD; k0 += 32) {
                float4 a0 = *(const float4*)(ap + k0);
                float4 a1 = *(const float4*)(ap + k0 + 4);
                u16x8 au;
                au[0] = f2bf(a0.x); au[1] = f2bf(a0.y); au[2] = f2bf(a0.z); au[3] = f2bf(a0.w);
                au[4] = f2bf(a1.x); au[5] = f2bf(a1.y); au[6] = f2bf(a1.z); au[7] = f2bf(a1.w);
                bf16x8 a = __builtin_bit_cast(bf16x8, au);
#pragma unroll
                for (int n = 0; n < 4; n++) {
                    bf16x8 b = *(const bf16x8*)(bp + (size_t)n * 16 * DD + k0);
                    acc[n] = __builtin_amdgcn_mfma_f32_16x16x32_bf16(a, b, acc[n], 0, 0, 0);
                }
            }
            int dcol = lane & 15;
            int dr0 = (lane >> 4) * 4;
#pragma unroll
            for (int n = 0; n < 4; n++) {
                int col = col0 + n * 16 + dcol;
                unsigned short* dst = (col < 512) ? h : g;
                int cc = col & 511;
#pragma unroll
                for (int rr = 0; rr < 4; rr++) {
                    int mr = row0 + dr0 + rr;
                    dst[(size_t)mr * 512 + cc] = f2bf(acc[n][rr]);
                }
            }
        }
    } else {
        // ---- projections: rows pid*4+wave; 6 dot products vs x-row ----
        int pid = bid - 4608;                        // 0..1535
        int row = pid * 4 + wave;
        int k0 = lane * 8;
        const float* xr_ = x + (size_t)row * DD + k0;
        float4 v0 = *(const float4*)xr_;
        float4 v1 = *(const float4*)(xr_ + 4);
        float xv[8] = {v0.x, v0.y, v0.z, v0.w, v1.x, v1.y, v1.z, v1.w};
        float d[6] = {0, 0, 0, 0, 0, 0};
        const float* srcs[6] = {Wa + k0, Wa + 512 + k0, Wb + k0, Wb + 512 + k0, wsl + k0, wsr + k0};
#pragma unroll
        for (int q = 0; q < 6; q++) {
            float4 w0 = *(const float4*)srcs[q];
            float4 w1 = *(const float4*)(srcs[q] + 4);
            float wv[8] = {w0.x, w0.y, w0.z, w0.w, w1.x, w1.y, w1.z, w1.w};
#pragma unroll
            for (int j = 0; j < 8; j++) d[q] += xv[j] * wv[j];
        }
#pragma unroll
        for (int off = 32; off; off >>= 1)
#pragma unroll
            for (int q = 0; q < 6; q++) d[q] += __shfl_down(d[q], off);
        if (lane == 0) {
            xal[row] = d[0]; xar[row] = d[1];
            xbl[row] = d[2]; xbr[row] = d[3];
            sl[row] = d[4]; sr[row] = d[5];
        }
    }
}

// ===== d3: k_final — gates + attention normalize + gathers + epilogue (idx lists) =====
__global__ __launch_bounds__(256) void k_final(
    const int* __restrict__ idxA, const int* __restrict__ cntA,
    const int* __restrict__ idxB, const int* __restrict__ cntB,
    const unsigned short* __restrict__ h, const unsigned short* __restrict__ g,
    const float* __restrict__ sl, const float* __restrict__ sr,
    const float* __restrict__ xal, const float* __restrict__ xar,
    const float* __restrict__ xbl, const float* __restrict__ xbr,
    const float* __restrict__ ba, const float* __restrict__ bb,
    const float* __restrict__ bias, float* __restrict__ out) {
    int i = blockIdx.x;
    int tid = threadIdx.x;
    __shared__ float w[CAP];
    __shared__ int ja[CAP], jb[CAP];
    __shared__ float s_denom, s_ga, s_gb;

    int cA = cntA[i]; cA = cA > CAP ? CAP : cA;
    int cB = cntB[i]; cB = cB > CAP ? CAP : cB;
    if (tid < cA) {
        int j = idxA[(size_t)i * CAP + tid];
        ja[tid] = j;
        float s = sl[i] + sr[j];
        float lrelu = s > 0.f ? s : 0.01f * s;
        w[tid] = expf(-lrelu);
    }
    if (tid < cB) jb[tid] = idxB[(size_t)i * CAP + tid];
    __syncthreads();

    if (tid < 64) {
        float p = 0.f, gasum = 0.f, gbsum = 0.f;
        for (int t = tid; t < cA; t += 64) { p += w[t]; gasum += xal[ja[t]]; }
        for (int t = tid; t < cB; t += 64) gbsum += xbl[jb[t]];
#pragma unroll
        for (int off = 32; off; off >>= 1) {
            p += __shfl_down(p, off);
            gasum += __shfl_down(gasum, off);
            gbsum += __shfl_down(gbsum, off);
        }
        if (tid == 0) {
            s_denom = p;
            s_ga = sigmoidf_(gasum + xar[i] + ba[0]);
            s_gb = sigmoidf_(gbsum + xbr[i] + bb[0]);
        }
    }
    __syncthreads();
    float inv = 1.f / (s_denom + 1e-5f);
    float ga = s_ga, gb = s_gb;

    int d0 = tid * 2;
    float a0 = 0, a1 = 0, b0 = 0, b1 = 0;
#pragma unroll 4
    for (int t = 0; t < cA; t++) {
        unsigned hv = *(const unsigned*)(h + (size_t)ja[t] * 512 + d0);
        float wt_ = w[t];
        a0 += wt_ * bf2f((unsigned short)(hv & 0xffff));
        a1 += wt_ * bf2f((unsigned short)(hv >> 16));
    }
#pragma unroll 4
    for (int t = 0; t < cB; t++) {
        unsigned gv = *(const unsigned*)(g + (size_t)jb[t] * 512 + d0);
        b0 += bf2f((unsigned short)(gv & 0xffff));
        b1 += bf2f((unsigned short)(gv >> 16));
    }
    float z0 = ga * (a0 * inv) + gb * (b0 + bias[d0]);
    float z1 = ga * (a1 * inv) + gb * (b1 + bias[d0 + 1]);
    out[(size_t)i * 512 + d0]     = sigmoidf_(z0);
    out[(size_t)i * 512 + d0 + 1] = sigmoidf_(z1);
}

extern "C" void kernel_launch(void* const* d_in, const int* in_sizes, int n_in,
                              void* d_out, int out_size, void* d_ws, size_t ws_size,
                              hipStream_t stream) {
    const float* x    = (const float*)d_in[0];
    const float* adjA = (const float*)d_in[1];
    const float* adjB = (const float*)d_in[2];
    const float* Wsa  = (const float*)d_in[3];
    const float* a_sa = (const float*)d_in[4];
    const float* Wg   = (const float*)d_in[5];
    const float* bg   = (const float*)d_in[6];
    const float* Wa   = (const float*)d_in[7];
    const float* ba   = (const float*)d_in[8];
    const float* Wb   = (const float*)d_in[9];
    const float* bb   = (const float*)d_in[10];
    float* out = (float*)d_out;

    char* ws = (char*)d_ws;
    size_t off = 0;
    auto alloc = [&](size_t bytes) -> void* {
        void* p = ws + off;
        off += (bytes + 255) & ~(size_t)255;
        return p;
    };
    unsigned short* wt = (unsigned short*)alloc((size_t)1024 * DD * 2);
    unsigned short* h  = (unsigned short*)alloc((size_t)NN * DD * 2);
    unsigned short* g  = (unsigned short*)alloc((size_t)NN * DD * 2);
    int* idxA = (int*)alloc((size_t)NN * CAP * 4);
    int* idxB = (int*)alloc((size_t)NN * CAP * 4);
    int* cntA = (int*)alloc((size_t)NN * 4);
    int* cntB = (int*)alloc((size_t)NN * 4);
    float* xal = (float*)alloc((size_t)NN * 4);
    float* xar = (float*)alloc((size_t)NN * 4);
    float* xbl = (float*)alloc((size_t)NN * 4);
    float* xbr = (float*)alloc((size_t)NN * 4);
    float* sl  = (float*)alloc((size_t)NN * 4);
    float* sr  = (float*)alloc((size_t)NN * 4);
    float* wsl = (float*)alloc((size_t)DD * 4);
    float* wsr = (float*)alloc((size_t)DD * 4);

    // d1: W^T (bf16) + w_sl/w_sr
    k_prep<<<256, 256, 0, stream>>>(Wsa, Wg, a_sa, wt, wsl, wsr);
    // d2: nt row-scan (compact idx, no atomics) + GEMM + projections
    k_fused<<<6144, 256, 0, stream>>>(x, (const bf16_t*)wt, adjA, adjB, Wa, Wb, wsl, wsr,
                                      idxA, idxB, cntA, cntB, h, g,
                                      xal, xar, xbl, xbr, sl, sr);
    // d3: gates + attention + GCN gather + sigmoid epilogue
    k_final<<<NN, 256, 0, stream>>>(idxA, cntA, idxB, cntB, h, g, sl, sr,
                                    xal, xar, xbl, xbr, ba, bb, bg, out);
}

// Round 11
// 158.375 us; speedup vs baseline: 1.1162x; 1.0405x over previous
//
#include <hip/hip_runtime.h>
#include <math.h>

#define NN 6144
#define DD 512
#define CAP 128

typedef __bf16 bf16_t;
typedef __bf16 bf16x8 __attribute__((ext_vector_type(8)));
typedef unsigned short u16x8 __attribute__((ext_vector_type(8)));
typedef float f32x4 __attribute__((ext_vector_type(4)));
typedef unsigned u32x4 __attribute__((ext_vector_type(4)));

__device__ __forceinline__ float bf2f(unsigned short u) {
    unsigned v = ((unsigned)u) << 16;
    return __builtin_bit_cast(float, v);
}
__device__ __forceinline__ unsigned short f2bf(float f) {
    unsigned u = __builtin_bit_cast(unsigned, f);
    u += 0x7fffu + ((u >> 16) & 1u);   // round-to-nearest-even
    return (unsigned short)(u >> 16);
}
__device__ __forceinline__ float sigmoidf_(float z) { return 1.0f / (1.0f + expf(-z)); }

// =========== d1: k_prep — wt transpose (blocks 0..127) + w_sl/w_sr (blocks 128..255) ===========
__global__ __launch_bounds__(256) void k_prep(const float* __restrict__ Wsa,
                                              const float* __restrict__ Wg,
                                              const float* __restrict__ a_sa,
                                              unsigned short* __restrict__ wt,
                                              float* __restrict__ wsl, float* __restrict__ wsr) {
    __shared__ float s[64][65];
    int bid = blockIdx.x;
    int wave = threadIdx.x >> 6, lane = threadIdx.x & 63;
    if (bid < 128) {
        int n0 = (bid & 15) * 64;
        int k0 = (bid >> 4) * 64;
        int tx = threadIdx.x & 63, ty = threadIdx.x >> 6;
        const float* src = (n0 < 512) ? Wsa : Wg;
        int nn0 = n0 & 511;
#pragma unroll
        for (int kk = 0; kk < 64; kk += 4)
            s[kk + ty][tx] = src[(size_t)(k0 + kk + ty) * 512 + nn0 + tx];
        __syncthreads();
#pragma unroll
        for (int nn = 0; nn < 64; nn += 4)
            wt[(size_t)(n0 + nn + ty) * 512 + k0 + tx] = f2bf(s[tx][nn + ty]);
    } else {
        int k = (bid - 128) * 4 + wave;         // 0..511
        int n0 = lane * 8;
        const float* wr = Wsa + (size_t)k * 512 + n0;
        float4 w0 = *(const float4*)wr, w1 = *(const float4*)(wr + 4);
        float4 l0 = *(const float4*)(a_sa + n0), l1 = *(const float4*)(a_sa + n0 + 4);
        float4 r0 = *(const float4*)(a_sa + 512 + n0), r1 = *(const float4*)(a_sa + 512 + n0 + 4);
        float sl_ = w0.x*l0.x + w0.y*l0.y + w0.z*l0.z + w0.w*l0.w
                  + w1.x*l1.x + w1.y*l1.y + w1.z*l1.z + w1.w*l1.w;
        float sr_ = w0.x*r0.x + w0.y*r0.y + w0.z*r0.z + w0.w*r0.w
                  + w1.x*r1.x + w1.y*r1.y + w1.z*r1.z + w1.w*r1.w;
#pragma unroll
        for (int off = 32; off; off >>= 1) { sl_ += __shfl_down(sl_, off); sr_ += __shfl_down(sr_, off); }
        if (lane == 0) { wsl[k] = sl_; wsr[k] = sr_; }
    }
}

// ===== d2: k_fused — {nt row-scan -> compact idx} + {MFMA GEMM} + {projections} =====
// blocks [0,4608): bid%3<2 -> scan (4 waves x 1 row);  bid%3==2 -> GEMM tile.
// blocks [4608,6144): per-row 6-dot projections.
__global__ __launch_bounds__(256) void k_fused(const float* __restrict__ x,
                                               const bf16_t* __restrict__ wt,
                                               const float* __restrict__ adjA,
                                               const float* __restrict__ adjB,
                                               const float* __restrict__ Wa,
                                               const float* __restrict__ Wb,
                                               const float* __restrict__ wsl,
                                               const float* __restrict__ wsr,
                                               int* __restrict__ idxA, int* __restrict__ idxB,
                                               int* __restrict__ cntA, int* __restrict__ cntB,
                                               unsigned short* __restrict__ h,
                                               unsigned short* __restrict__ g,
                                               float* __restrict__ xal, float* __restrict__ xar,
                                               float* __restrict__ xbl, float* __restrict__ xbr,
                                               float* __restrict__ sl, float* __restrict__ sr) {
    int bid = blockIdx.x;
    int wave = threadIdx.x >> 6, lane = threadIdx.x & 63;
    if (bid < 4608) {
        int grp = bid % 3;
        if (grp < 2) {
            // ---- scan: one wave = one adjacency row, 24 nt loads, prefix-compact ----
            int sid = (bid / 3) * 2 + grp;          // 0..3071
            int row = sid * 4 + wave;               // 0..12287
            int which = row >= NN;
            int r = which ? row - NN : row;
            const float* adj = which ? adjB : adjA;
            int* idx = (which ? idxB : idxA) + (size_t)r * CAP;
            int* cnt = which ? cntB : cntA;

            const u32x4* arow = (const u32x4*)(adj + (size_t)r * NN) + lane;
            u32x4 v[24];
#pragma unroll
            for (int j = 0; j < 24; j++) v[j] = __builtin_nontemporal_load(arow + j * 64);

            unsigned m[3] = {0, 0, 0};
#pragma unroll
            for (int j = 0; j < 24; j++) {
                unsigned w_ = (j >> 3);
                unsigned sh = (j & 7) * 4;
                m[w_] |= (v[j][0] != 0u ? 1u : 0u) << sh;
                m[w_] |= (v[j][1] != 0u ? 1u : 0u) << (sh + 1);
                m[w_] |= (v[j][2] != 0u ? 1u : 0u) << (sh + 2);
                m[w_] |= (v[j][3] != 0u ? 1u : 0u) << (sh + 3);
            }
            int c = __popc(m[0]) + __popc(m[1]) + __popc(m[2]);
            int p = c;
#pragma unroll
            for (int off = 1; off < 64; off <<= 1) {
                int t = __shfl_up(p, off);
                if (lane >= off) p += t;
            }
            int pos = p - c;                 // exclusive prefix
            int total = __shfl(p, 63);
#pragma unroll
            for (int w_ = 0; w_ < 3; w_++) {
                unsigned mm = m[w_];
                while (mm) {
                    int b = __ffs(mm) - 1;
                    mm &= mm - 1;
                    int e = w_ * 32 + b;               // element 0..95 within lane
                    int col = (e >> 2) * 256 + lane * 4 + (e & 3);
                    if (pos < CAP) idx[pos] = col;
                    pos++;
                }
            }
            if (lane == 0) cnt[r] = total > CAP ? CAP : total;
        } else {
            // ---- GEMM tile: 64 rows x 64 cols, MFMA 16x16x32, A cvt in-register ----
            int tt = bid / 3;                        // 0..1535
            int row0 = (tt % (NN / 64)) * 64 + wave * 16;
            int col0 = (tt / (NN / 64)) * 64;
            int lr = lane & 15;
            int kg = (lane >> 4) * 8;

            f32x4 acc[4] = {{0,0,0,0},{0,0,0,0},{0,0,0,0},{0,0,0,0}};
            const float* ap = x + (size_t)(row0 + lr) * DD + kg;
            const bf16_t* bp = wt + (size_t)(col0 + lr) * DD + kg;

            for (int k0 = 0; k0 < DD; k0 += 32) {
                float4 a0 = *(const float4*)(ap + k0);
                float4 a1 = *(const float4*)(ap + k0 + 4);
                u16x8 au;
                au[0] = f2bf(a0.x); au[1] = f2bf(a0.y); au[2] = f2bf(a0.z); au[3] = f2bf(a0.w);
                au[4] = f2bf(a1.x); au[5] = f2bf(a1.y); au[6] = f2bf(a1.z); au[7] = f2bf(a1.w);
                bf16x8 a = __builtin_bit_cast(bf16x8, au);
#pragma unroll
                for (int n = 0; n < 4; n++) {
                    bf16x8 b = *(const bf16x8*)(bp + (size_t)n * 16 * DD + k0);
                    acc[n] = __builtin_amdgcn_mfma_f32_16x16x32_bf16(a, b, acc[n], 0, 0, 0);
                }
            }
            int dcol = lane & 15;
            int dr0 = (lane >> 4) * 4;
#pragma unroll
            for (int n = 0; n < 4; n++) {
                int col = col0 + n * 16 + dcol;
                unsigned short* dst = (col < 512) ? h : g;
                int cc = col & 511;
#pragma unroll
                for (int rr = 0; rr < 4; rr++) {
                    int mr = row0 + dr0 + rr;
                    dst[(size_t)mr * 512 + cc] = f2bf(acc[n][rr]);
                }
            }
        }
    } else {
        // ---- projections: rows pid*4+wave; 6 dot products vs x-row ----
        int pid = bid - 4608;                        // 0..1535
        int row = pid * 4 + wave;
        int k0 = lane * 8;
        const float* xr_ = x + (size_t)row * DD + k0;
        float4 v0 = *(const float4*)xr_;
        float4 v1 = *(const float4*)(xr_ + 4);
        float xv[8] = {v0.x, v0.y, v0.z, v0.w, v1.x, v1.y, v1.z, v1.w};
        float d[6] = {0, 0, 0, 0, 0, 0};
        const float* srcs[6] = {Wa + k0, Wa + 512 + k0, Wb + k0, Wb + 512 + k0, wsl + k0, wsr + k0};
#pragma unroll
        for (int q = 0; q < 6; q++) {
            float4 w0 = *(const float4*)srcs[q];
            float4 w1 = *(const float4*)(srcs[q] + 4);
            float wv[8] = {w0.x, w0.y, w0.z, w0.w, w1.x, w1.y, w1.z, w1.w};
#pragma unroll
            for (int j = 0; j < 8; j++) d[q] += xv[j] * wv[j];
        }
#pragma unroll
        for (int off = 32; off; off >>= 1)
#pragma unroll
            for (int q = 0; q < 6; q++) d[q] += __shfl_down(d[q], off);
        if (lane == 0) {
            xal[row] = d[0]; xar[row] = d[1];
            xbl[row] = d[2]; xbr[row] = d[3];
            sl[row] = d[4]; sr[row] = d[5];
        }
    }
}

// ===== d3: k_final — wave-per-row: gates + attention + interleaved A/B gathers + epilogue =====
// grid 1536 x 256; wave handles row i = bid*4+wave, lane owns dims [lane*8, lane*8+8).
__global__ __launch_bounds__(256) void k_final(
    const int* __restrict__ idxA, const int* __restrict__ cntA,
    const int* __restrict__ idxB, const int* __restrict__ cntB,
    const unsigned short* __restrict__ h, const unsigned short* __restrict__ g,
    const float* __restrict__ sl, const float* __restrict__ sr,
    const float* __restrict__ xal, const float* __restrict__ xar,
    const float* __restrict__ xbl, const float* __restrict__ xbr,
    const float* __restrict__ ba, const float* __restrict__ bb,
    const float* __restrict__ bias, float* __restrict__ out) {
    int wave = threadIdx.x >> 6, lane = threadIdx.x & 63;
    int i = blockIdx.x * 4 + wave;

    int cA = cntA[i]; cA = cA > CAP ? CAP : cA;
    int cB = cntB[i]; cB = cB > CAP ? CAP : cB;
    const int* ia = idxA + (size_t)i * CAP;
    const int* ib = idxB + (size_t)i * CAP;

    int j0 = (lane < cA) ? ia[lane] : 0;
    int j1 = (lane + 64 < cA) ? ia[lane + 64] : 0;
    int jb0 = (lane < cB) ? ib[lane] : 0;
    int jb1 = (lane + 64 < cB) ? ib[lane + 64] : 0;

    float sli = sl[i];
    float w0 = 0.f, w1 = 0.f, psum = 0.f, gas = 0.f, gbs = 0.f;
    if (lane < cA) {
        float s = sli + sr[j0];
        float lr = s > 0.f ? s : 0.01f * s;
        w0 = expf(-lr); psum += w0; gas += xal[j0];
    }
    if (lane + 64 < cA) {
        float s = sli + sr[j1];
        float lr = s > 0.f ? s : 0.01f * s;
        w1 = expf(-lr); psum += w1; gas += xal[j1];
    }
    if (lane < cB) gbs += xbl[jb0];
    if (lane + 64 < cB) gbs += xbl[jb1];
#pragma unroll
    for (int off = 1; off < 64; off <<= 1) {
        psum += __shfl_xor(psum, off);
        gas += __shfl_xor(gas, off);
        gbs += __shfl_xor(gbs, off);
    }
    float inv = 1.f / (psum + 1e-5f);
    float ga = sigmoidf_(gas + xar[i] + ba[0]);
    float gb = sigmoidf_(gbs + xbr[i] + bb[0]);

    const u32x4* h4 = (const u32x4*)h;
    const u32x4* g4 = (const u32x4*)g;
    float accA[8] = {0, 0, 0, 0, 0, 0, 0, 0};
    float accB[8] = {0, 0, 0, 0, 0, 0, 0, 0};
    int tmax = cA > cB ? cA : cB;
#pragma unroll 2
    for (int t = 0; t < tmax; t++) {
        if (t < cA) {
            int j = __shfl(t < 64 ? j0 : j1, t & 63);
            float wt_ = __shfl(t < 64 ? w0 : w1, t & 63);
            u32x4 hv = h4[(size_t)j * 64 + lane];
#pragma unroll
            for (int q = 0; q < 4; q++) {
                accA[2 * q]     += wt_ * bf2f((unsigned short)(hv[q] & 0xffff));
                accA[2 * q + 1] += wt_ * bf2f((unsigned short)(hv[q] >> 16));
            }
        }
        if (t < cB) {
            int j = __shfl(t < 64 ? jb0 : jb1, t & 63);
            u32x4 gv = g4[(size_t)j * 64 + lane];
#pragma unroll
            for (int q = 0; q < 4; q++) {
                accB[2 * q]     += bf2f((unsigned short)(gv[q] & 0xffff));
                accB[2 * q + 1] += bf2f((unsigned short)(gv[q] >> 16));
            }
        }
    }
    int d0 = lane * 8;
    float4 bs0 = *(const float4*)(bias + d0);
    float4 bs1 = *(const float4*)(bias + d0 + 4);
    float bv[8] = {bs0.x, bs0.y, bs0.z, bs0.w, bs1.x, bs1.y, bs1.z, bs1.w};
    float ov[8];
#pragma unroll
    for (int q = 0; q < 8; q++)
        ov[q] = sigmoidf_(ga * (accA[q] * inv) + gb * (accB[q] + bv[q]));
    float4 o0 = {ov[0], ov[1], ov[2], ov[3]};
    float4 o1 = {ov[4], ov[5], ov[6], ov[7]};
    *(float4*)(out + (size_t)i * 512 + d0) = o0;
    *(float4*)(out + (size_t)i * 512 + d0 + 4) = o1;
}

extern "C" void kernel_launch(void* const* d_in, const int* in_sizes, int n_in,
                              void* d_out, int out_size, void* d_ws, size_t ws_size,
                              hipStream_t stream) {
    const float* x    = (const float*)d_in[0];
    const float* adjA = (const float*)d_in[1];
    const float* adjB = (const float*)d_in[2];
    const float* Wsa  = (const float*)d_in[3];
    const float* a_sa = (const float*)d_in[4];
    const float* Wg   = (const float*)d_in[5];
    const float* bg   = (const float*)d_in[6];
    const float* Wa   = (const float*)d_in[7];
    const float* ba   = (const float*)d_in[8];
    const float* Wb   = (const float*)d_in[9];
    const float* bb   = (const float*)d_in[10];
    float* out = (float*)d_out;

    char* ws = (char*)d_ws;
    size_t off = 0;
    auto alloc = [&](size_t bytes) -> void* {
        void* p = ws + off;
        off += (bytes + 255) & ~(size_t)255;
        return p;
    };
    unsigned short* wt = (unsigned short*)alloc((size_t)1024 * DD * 2);
    unsigned short* h  = (unsigned short*)alloc((size_t)NN * DD * 2);
    unsigned short* g  = (unsigned short*)alloc((size_t)NN * DD * 2);
    int* idxA = (int*)alloc((size_t)NN * CAP * 4);
    int* idxB = (int*)alloc((size_t)NN * CAP * 4);
    int* cntA = (int*)alloc((size_t)NN * 4);
    int* cntB = (int*)alloc((size_t)NN * 4);
    float* xal = (float*)alloc((size_t)NN * 4);
    float* xar = (float*)alloc((size_t)NN * 4);
    float* xbl = (float*)alloc((size_t)NN * 4);
    float* xbr = (float*)alloc((size_t)NN * 4);
    float* sl  = (float*)alloc((size_t)NN * 4);
    float* sr  = (float*)alloc((size_t)NN * 4);
    float* wsl = (float*)alloc((size_t)DD * 4);
    float* wsr = (float*)alloc((size_t)DD * 4);

    // d1: W^T (bf16) + w_sl/w_sr
    k_prep<<<256, 256, 0, stream>>>(Wsa, Wg, a_sa, wt, wsl, wsr);
    // d2: nt row-scan (compact idx, no atomics) + GEMM + projections
    k_fused<<<6144, 256, 0, stream>>>(x, (const bf16_t*)wt, adjA, adjB, Wa, Wb, wsl, wsr,
                                      idxA, idxB, cntA, cntB, h, g,
                                      xal, xar, xbl, xbr, sl, sr);
    // d3: wave-per-row gates + attention + interleaved gathers + sigmoid epilogue
    k_final<<<NN / 4, 256, 0, stream>>>(idxA, cntA, idxB, cntB, h, g, sl, sr,
                                        xal, xar, xbl, xbr, ba, bb, bg, out);
}

// Round 12
// 158.355 us; speedup vs baseline: 1.1163x; 1.0001x over previous
//
#include <hip/hip_runtime.h>
#include <math.h>

#define NN 6144
#define DD 512
#define CAP 128

typedef __bf16 bf16_t;
typedef __bf16 bf16x8 __attribute__((ext_vector_type(8)));
typedef unsigned short u16x8 __attribute__((ext_vector_type(8)));
typedef float f32x4 __attribute__((ext_vector_type(4)));
typedef unsigned u32x4 __attribute__((ext_vector_type(4)));

__device__ __forceinline__ float bf2f(unsigned short u) {
    unsigned v = ((unsigned)u) << 16;
    return __builtin_bit_cast(float, v);
}
__device__ __forceinline__ unsigned short f2bf(float f) {
    unsigned u = __builtin_bit_cast(unsigned, f);
    u += 0x7fffu + ((u >> 16) & 1u);   // round-to-nearest-even
    return (unsigned short)(u >> 16);
}
__device__ __forceinline__ float sigmoidf_(float z) { return 1.0f / (1.0f + expf(-z)); }

// =========== d1: k_prep — wt transpose (blocks 0..127) + w_sl/w_sr (blocks 128..255) ===========
__global__ __launch_bounds__(256) void k_prep(const float* __restrict__ Wsa,
                                              const float* __restrict__ Wg,
                                              const float* __restrict__ a_sa,
                                              unsigned short* __restrict__ wt,
                                              float* __restrict__ wsl, float* __restrict__ wsr) {
    __shared__ float s[64][65];
    int bid = blockIdx.x;
    int wave = threadIdx.x >> 6, lane = threadIdx.x & 63;
    if (bid < 128) {
        int n0 = (bid & 15) * 64;
        int k0 = (bid >> 4) * 64;
        int tx = threadIdx.x & 63, ty = threadIdx.x >> 6;
        const float* src = (n0 < 512) ? Wsa : Wg;
        int nn0 = n0 & 511;
#pragma unroll
        for (int kk = 0; kk < 64; kk += 4)
            s[kk + ty][tx] = src[(size_t)(k0 + kk + ty) * 512 + nn0 + tx];
        __syncthreads();
#pragma unroll
        for (int nn = 0; nn < 64; nn += 4)
            wt[(size_t)(n0 + nn + ty) * 512 + k0 + tx] = f2bf(s[tx][nn + ty]);
    } else {
        int k = (bid - 128) * 4 + wave;         // 0..511
        int n0 = lane * 8;
        const float* wr = Wsa + (size_t)k * 512 + n0;
        float4 w0 = *(const float4*)wr, w1 = *(const float4*)(wr + 4);
        float4 l0 = *(const float4*)(a_sa + n0), l1 = *(const float4*)(a_sa + n0 + 4);
        float4 r0 = *(const float4*)(a_sa + 512 + n0), r1 = *(const float4*)(a_sa + 512 + n0 + 4);
        float sl_ = w0.x*l0.x + w0.y*l0.y + w0.z*l0.z + w0.w*l0.w
                  + w1.x*l1.x + w1.y*l1.y + w1.z*l1.z + w1.w*l1.w;
        float sr_ = w0.x*r0.x + w0.y*r0.y + w0.z*r0.z + w0.w*r0.w
                  + w1.x*r1.x + w1.y*r1.y + w1.z*r1.z + w1.w*r1.w;
#pragma unroll
        for (int off = 32; off; off >>= 1) { sl_ += __shfl_down(sl_, off); sr_ += __shfl_down(sr_, off); }
        if (lane == 0) { wsl[k] = sl_; wsr[k] = sr_; }
    }
}

// ===== d2: k_fused — {nt row-scan -> compact idx} + {MFMA GEMM} + {projections} =====
// blocks [0,4608): bid%3<2 -> scan (4 waves x 1 row);  bid%3==2 -> GEMM tile.
// blocks [4608,6144): per-row 6-dot projections.
__global__ __launch_bounds__(256) void k_fused(const float* __restrict__ x,
                                               const bf16_t* __restrict__ wt,
                                               const float* __restrict__ adjA,
                                               const float* __restrict__ adjB,
                                               const float* __restrict__ Wa,
                                               const float* __restrict__ Wb,
                                               const float* __restrict__ wsl,
                                               const float* __restrict__ wsr,
                                               int* __restrict__ idxA, int* __restrict__ idxB,
                                               int* __restrict__ cntA, int* __restrict__ cntB,
                                               unsigned short* __restrict__ h,
                                               unsigned short* __restrict__ g,
                                               float* __restrict__ xal, float* __restrict__ xar,
                                               float* __restrict__ xbl, float* __restrict__ xbr,
                                               float* __restrict__ sl, float* __restrict__ sr) {
    int bid = blockIdx.x;
    int wave = threadIdx.x >> 6, lane = threadIdx.x & 63;
    if (bid < 4608) {
        int grp = bid % 3;
        if (grp < 2) {
            // ---- scan: one wave = one adjacency row, 24 nt loads, prefix-compact ----
            int sid = (bid / 3) * 2 + grp;          // 0..3071
            int row = sid * 4 + wave;               // 0..12287
            int which = row >= NN;
            int r = which ? row - NN : row;
            const float* adj = which ? adjB : adjA;
            int* idx = (which ? idxB : idxA) + (size_t)r * CAP;
            int* cnt = which ? cntB : cntA;

            const u32x4* arow = (const u32x4*)(adj + (size_t)r * NN) + lane;
            u32x4 v[24];
#pragma unroll
            for (int j = 0; j < 24; j++) v[j] = __builtin_nontemporal_load(arow + j * 64);

            unsigned m[3] = {0, 0, 0};
#pragma unroll
            for (int j = 0; j < 24; j++) {
                unsigned w_ = (j >> 3);
                unsigned sh = (j & 7) * 4;
                m[w_] |= (v[j][0] != 0u ? 1u : 0u) << sh;
                m[w_] |= (v[j][1] != 0u ? 1u : 0u) << (sh + 1);
                m[w_] |= (v[j][2] != 0u ? 1u : 0u) << (sh + 2);
                m[w_] |= (v[j][3] != 0u ? 1u : 0u) << (sh + 3);
            }
            int c = __popc(m[0]) + __popc(m[1]) + __popc(m[2]);
            int p = c;
#pragma unroll
            for (int off = 1; off < 64; off <<= 1) {
                int t = __shfl_up(p, off);
                if (lane >= off) p += t;
            }
            int pos = p - c;                 // exclusive prefix
            int total = __shfl(p, 63);
#pragma unroll
            for (int w_ = 0; w_ < 3; w_++) {
                unsigned mm = m[w_];
                while (mm) {
                    int b = __ffs(mm) - 1;
                    mm &= mm - 1;
                    int e = w_ * 32 + b;               // element 0..95 within lane
                    int col = (e >> 2) * 256 + lane * 4 + (e & 3);
                    if (pos < CAP) idx[pos] = col;
                    pos++;
                }
            }
            if (lane == 0) cnt[r] = total > CAP ? CAP : total;
        } else {
            // ---- GEMM tile: 64 rows x 64 cols, MFMA 16x16x32, A cvt in-register ----
            int tt = bid / 3;                        // 0..1535
            int row0 = (tt % (NN / 64)) * 64 + wave * 16;
            int col0 = (tt / (NN / 64)) * 64;
            int lr = lane & 15;
            int kg = (lane >> 4) * 8;

            f32x4 acc[4] = {{0,0,0,0},{0,0,0,0},{0,0,0,0},{0,0,0,0}};
            const float* ap = x + (size_t)(row0 + lr) * DD + kg;
            const bf16_t* bp = wt + (size_t)(col0 + lr) * DD + kg;

            for (int k0 = 0; k0 < DD; k0 += 32) {
                float4 a0 = *(const float4*)(ap + k0);
                float4 a1 = *(const float4*)(ap + k0 + 4);
                u16x8 au;
                au[0] = f2bf(a0.x); au[1] = f2bf(a0.y); au[2] = f2bf(a0.z); au[3] = f2bf(a0.w);
                au[4] = f2bf(a1.x); au[5] = f2bf(a1.y); au[6] = f2bf(a1.z); au[7] = f2bf(a1.w);
                bf16x8 a = __builtin_bit_cast(bf16x8, au);
#pragma unroll
                for (int n = 0; n < 4; n++) {
                    bf16x8 b = *(const bf16x8*)(bp + (size_t)n * 16 * DD + k0);
                    acc[n] = __builtin_amdgcn_mfma_f32_16x16x32_bf16(a, b, acc[n], 0, 0, 0);
                }
            }
            int dcol = lane & 15;
            int dr0 = (lane >> 4) * 4;
#pragma unroll
            for (int n = 0; n < 4; n++) {
                int col = col0 + n * 16 + dcol;
                unsigned short* dst = (col < 512) ? h : g;
                int cc = col & 511;
#pragma unroll
                for (int rr = 0; rr < 4; rr++) {
                    int mr = row0 + dr0 + rr;
                    dst[(size_t)mr * 512 + cc] = f2bf(acc[n][rr]);
                }
            }
        }
    } else {
        // ---- projections: rows pid*4+wave; 6 dot products vs x-row ----
        int pid = bid - 4608;                        // 0..1535
        int row = pid * 4 + wave;
        int k0 = lane * 8;
        const float* xr_ = x + (size_t)row * DD + k0;
        float4 v0 = *(const float4*)xr_;
        float4 v1 = *(const float4*)(xr_ + 4);
        float xv[8] = {v0.x, v0.y, v0.z, v0.w, v1.x, v1.y, v1.z, v1.w};
        float d[6] = {0, 0, 0, 0, 0, 0};
        const float* srcs[6] = {Wa + k0, Wa + 512 + k0, Wb + k0, Wb + 512 + k0, wsl + k0, wsr + k0};
#pragma unroll
        for (int q = 0; q < 6; q++) {
            float4 w0 = *(const float4*)srcs[q];
            float4 w1 = *(const float4*)(srcs[q] + 4);
            float wv[8] = {w0.x, w0.y, w0.z, w0.w, w1.x, w1.y, w1.z, w1.w};
#pragma unroll
            for (int j = 0; j < 8; j++) d[q] += xv[j] * wv[j];
        }
#pragma unroll
        for (int off = 32; off; off >>= 1)
#pragma unroll
            for (int q = 0; q < 6; q++) d[q] += __shfl_down(d[q], off);
        if (lane == 0) {
            xal[row] = d[0]; xar[row] = d[1];
            xbl[row] = d[2]; xbr[row] = d[3];
            sl[row] = d[4]; sr[row] = d[5];
        }
    }
}

// ===== d3: k_final — 2 waves per row: A-side (attn weighted gather) || B-side (GCN gather) =====
// grid 3072 x 256; block = 2 rows x 2 waves. side 0 = A, side 1 = B; combine via LDS.
__global__ __launch_bounds__(256) void k_final(
    const int* __restrict__ idxA, const int* __restrict__ cntA,
    const int* __restrict__ idxB, const int* __restrict__ cntB,
    const unsigned short* __restrict__ h, const unsigned short* __restrict__ g,
    const float* __restrict__ sl, const float* __restrict__ sr,
    const float* __restrict__ xal, const float* __restrict__ xar,
    const float* __restrict__ xbl, const float* __restrict__ xbr,
    const float* __restrict__ ba, const float* __restrict__ bb,
    const float* __restrict__ bias, float* __restrict__ out) {
    int wave = threadIdx.x >> 6, lane = threadIdx.x & 63;
    int rb = wave >> 1;                       // row within block: 0..1
    int side = wave & 1;                      // 0 = A-side, 1 = B-side
    int i = blockIdx.x * 2 + rb;

    __shared__ float s_accB[2][64][9];        // +1 pad: conflict-free scalar reads
    __shared__ float s_gb[2];

    float accL[8] = {0, 0, 0, 0, 0, 0, 0, 0};
    float inv = 0.f, ga = 0.f;

    if (side == 0) {
        // ---- A-side: weights + psum + gas + weighted gather ----
        int cA = cntA[i]; cA = cA > CAP ? CAP : cA;
        const int* ia = idxA + (size_t)i * CAP;
        int j0 = (lane < cA) ? ia[lane] : 0;
        int j1 = (lane + 64 < cA) ? ia[lane + 64] : 0;
        float sli = sl[i];
        float w0 = 0.f, w1 = 0.f, psum = 0.f, gas = 0.f;
        if (lane < cA) {
            float s = sli + sr[j0];
            float lr = s > 0.f ? s : 0.01f * s;
            w0 = expf(-lr); psum += w0; gas += xal[j0];
        }
        if (lane + 64 < cA) {
            float s = sli + sr[j1];
            float lr = s > 0.f ? s : 0.01f * s;
            w1 = expf(-lr); psum += w1; gas += xal[j1];
        }
#pragma unroll
        for (int off = 1; off < 64; off <<= 1) {
            psum += __shfl_xor(psum, off);
            gas += __shfl_xor(gas, off);
        }
        inv = 1.f / (psum + 1e-5f);
        ga = sigmoidf_(gas + xar[i] + ba[0]);

        const u32x4* h4 = (const u32x4*)h;
#pragma unroll 2
        for (int t = 0; t < cA; t++) {
            int j = __shfl(t < 64 ? j0 : j1, t & 63);
            float wt_ = __shfl(t < 64 ? w0 : w1, t & 63);
            u32x4 hv = h4[(size_t)j * 64 + lane];
#pragma unroll
            for (int q = 0; q < 4; q++) {
                accL[2 * q]     += wt_ * bf2f((unsigned short)(hv[q] & 0xffff));
                accL[2 * q + 1] += wt_ * bf2f((unsigned short)(hv[q] >> 16));
            }
        }
    } else {
        // ---- B-side: gbs + unweighted gather ----
        int cB = cntB[i]; cB = cB > CAP ? CAP : cB;
        const int* ib = idxB + (size_t)i * CAP;
        int jb0 = (lane < cB) ? ib[lane] : 0;
        int jb1 = (lane + 64 < cB) ? ib[lane + 64] : 0;
        float gbs = 0.f;
        if (lane < cB) gbs += xbl[jb0];
        if (lane + 64 < cB) gbs += xbl[jb1];
#pragma unroll
        for (int off = 1; off < 64; off <<= 1) gbs += __shfl_xor(gbs, off);
        float gb = sigmoidf_(gbs + xbr[i] + bb[0]);

        const u32x4* g4 = (const u32x4*)g;
#pragma unroll 2
        for (int t = 0; t < cB; t++) {
            int j = __shfl(t < 64 ? jb0 : jb1, t & 63);
            u32x4 gv = g4[(size_t)j * 64 + lane];
#pragma unroll
            for (int q = 0; q < 4; q++) {
                accL[2 * q]     += bf2f((unsigned short)(gv[q] & 0xffff));
                accL[2 * q + 1] += bf2f((unsigned short)(gv[q] >> 16));
            }
        }
#pragma unroll
        for (int q = 0; q < 8; q++) s_accB[rb][lane][q] = accL[q];
        if (lane == 0) s_gb[rb] = gb;
    }
    __syncthreads();
    if (side == 0) {
        float gb = s_gb[rb];
        int d0 = lane * 8;
        float4 bs0 = *(const float4*)(bias + d0);
        float4 bs1 = *(const float4*)(bias + d0 + 4);
        float bv[8] = {bs0.x, bs0.y, bs0.z, bs0.w, bs1.x, bs1.y, bs1.z, bs1.w};
        float ov[8];
#pragma unroll
        for (int q = 0; q < 8; q++)
            ov[q] = sigmoidf_(ga * (accL[q] * inv) + gb * (s_accB[rb][lane][q] + bv[q]));
        float4 o0 = {ov[0], ov[1], ov[2], ov[3]};
        float4 o1 = {ov[4], ov[5], ov[6], ov[7]};
        *(float4*)(out + (size_t)i * 512 + d0) = o0;
        *(float4*)(out + (size_t)i * 512 + d0 + 4) = o1;
    }
}

extern "C" void kernel_launch(void* const* d_in, const int* in_sizes, int n_in,
                              void* d_out, int out_size, void* d_ws, size_t ws_size,
                              hipStream_t stream) {
    const float* x    = (const float*)d_in[0];
    const float* adjA = (const float*)d_in[1];
    const float* adjB = (const float*)d_in[2];
    const float* Wsa  = (const float*)d_in[3];
    const float* a_sa = (const float*)d_in[4];
    const float* Wg   = (const float*)d_in[5];
    const float* bg   = (const float*)d_in[6];
    const float* Wa   = (const float*)d_in[7];
    const float* ba   = (const float*)d_in[8];
    const float* Wb   = (const float*)d_in[9];
    const float* bb   = (const float*)d_in[10];
    float* out = (float*)d_out;

    char* ws = (char*)d_ws;
    size_t off = 0;
    auto alloc = [&](size_t bytes) -> void* {
        void* p = ws + off;
        off += (bytes + 255) & ~(size_t)255;
        return p;
    };
    unsigned short* wt = (unsigned short*)alloc((size_t)1024 * DD * 2);
    unsigned short* h  = (unsigned short*)alloc((size_t)NN * DD * 2);
    unsigned short* g  = (unsigned short*)alloc((size_t)NN * DD * 2);
    int* idxA = (int*)alloc((size_t)NN * CAP * 4);
    int* idxB = (int*)alloc((size_t)NN * CAP * 4);
    int* cntA = (int*)alloc((size_t)NN * 4);
    int* cntB = (int*)alloc((size_t)NN * 4);
    float* xal = (float*)alloc((size_t)NN * 4);
    float* xar = (float*)alloc((size_t)NN * 4);
    float* xbl = (float*)alloc((size_t)NN * 4);
    float* xbr = (float*)alloc((size_t)NN * 4);
    float* sl  = (float*)alloc((size_t)NN * 4);
    float* sr  = (float*)alloc((size_t)NN * 4);
    float* wsl = (float*)alloc((size_t)DD * 4);
    float* wsr = (float*)alloc((size_t)DD * 4);

    // d1: W^T (bf16) + w_sl/w_sr
    k_prep<<<256, 256, 0, stream>>>(Wsa, Wg, a_sa, wt, wsl, wsr);
    // d2: nt row-scan (compact idx, no atomics) + GEMM + projections
    k_fused<<<6144, 256, 0, stream>>>(x, (const bf16_t*)wt, adjA, adjB, Wa, Wb, wsl, wsr,
                                      idxA, idxB, cntA, cntB, h, g,
                                      xal, xar, xbl, xbr, sl, sr);
    // d3: 2-waves-per-row gates + attention + split gathers + sigmoid epilogue
    k_final<<<NN / 2, 256, 0, stream>>>(idxA, cntA, idxB, cntB, h, g, sl, sr,
                                        xal, xar, xbl, xbr, ba, bb, bg, out);
}